// Round 5
// baseline (791.378 us; speedup 1.0000x reference)
//
#include <hip/hip_runtime.h>
#include <math.h>

#define NN 100000
#define EE 3200000
#define ET (EE + NN)
#define NG 64
#define NPB 128        // pool partial blocks
#define NBLK 391       // ceil(NN/256)

// windowed scatter params
#define SC_P 4         // passes (dst windows)
#define SC_BPP 1024    // blocks per pass
#define SC_W 25000     // nodes per window

// workspace layout (4-byte units)
#define OFF_XL1   0u
#define OFF_XR1   3200000u
#define OFF_H     6400000u
#define OFF_HL2   9600000u
#define OFF_HR2   16000000u
#define OFF_OUT2  0u           /* reuses XL1/XR1 (dead after layer 1) */
#define OFF_PPART 22400000u    /* NPB * 4160 = 532480 */
#define OFF_DEG   22932480u    /* 100096 */
#define OFF_RP    23032576u    /* 100096 (NN+1 used) */
#define OFF_CUR   23132672u    /* 100096 */
#define OFF_PART  23232768u    /* 512 */
#define OFF_TMP   23233280u    /* 100096 */
#define OFF_ESRC  23333376u    /* ET */
#define WS_UNITS  26633376u

__device__ __forceinline__ float lrelu(float v) { return v > 0.0f ? v : 0.2f * v; }

// ======================= CSR build =======================
__global__ __launch_bounds__(256) void k_count(const int* __restrict__ ei, int* __restrict__ deg) {
  for (int e = blockIdx.x * 256 + threadIdx.x; e < ET; e += gridDim.x * 256) {
    int d = (e < EE) ? ei[EE + e] : (e - EE);
    atomicAdd(deg + d, 1);
  }
}

__global__ __launch_bounds__(256) void k_scan1(const int* __restrict__ deg,
                                               int* __restrict__ tmp, int* __restrict__ part) {
  __shared__ int sd[256];
  int t = threadIdx.x, b = blockIdx.x, i = b * 256 + t;
  int v = (i < NN) ? deg[i] : 0;
  sd[t] = v;
  __syncthreads();
  for (int o = 1; o < 256; o <<= 1) {
    int u = (t >= o) ? sd[t - o] : 0;
    __syncthreads();
    sd[t] += u;
    __syncthreads();
  }
  tmp[i] = sd[t];
  if (t == 255) part[b] = sd[t];
}

__global__ __launch_bounds__(512) void k_scan2(int* __restrict__ part) {
  __shared__ int sd[512];
  int t = threadIdx.x;
  int v = (t < NBLK) ? part[t] : 0;
  sd[t] = v;
  __syncthreads();
  for (int o = 1; o < 512; o <<= 1) {
    int u = (t >= o) ? sd[t - o] : 0;
    __syncthreads();
    sd[t] += u;
    __syncthreads();
  }
  if (t < NBLK) part[t] = sd[t];
}

__global__ __launch_bounds__(256) void k_scan3(const int* __restrict__ deg,
                                               const int* __restrict__ tmp,
                                               const int* __restrict__ part,
                                               int* __restrict__ rp, int* __restrict__ cur) {
  int b = blockIdx.x, t = threadIdx.x, i = b * 256 + t;
  if (b == 0 && t == 0) rp[NN] = ET;
  if (i >= NN) return;
  int excl = tmp[i] - deg[i] + (b > 0 ? part[b - 1] : 0);
  rp[i] = excl;
  cur[i] = excl;
}

// windowed multi-pass scatter: pass = blockIdx/SC_BPP handles dst window only.
// Each dst belongs to exactly one pass -> order-independent correctness;
// dispatch order gives soft time-partitioning so the esrc write window (~3.3MB)
// stays L2-resident instead of streaming 199MB of partial-line writebacks.
__global__ __launch_bounds__(256) void k_scatterw(const int* __restrict__ ei,
                                                  int* __restrict__ cur,
                                                  int* __restrict__ esrc) {
  int pass = blockIdx.x / SC_BPP;
  int blk  = blockIdx.x % SC_BPP;
  int wlo = pass * SC_W;
  int whi = wlo + SC_W;
  for (long e = (long)blk * 256 + threadIdx.x; e < ET; e += (long)SC_BPP * 256) {
    int d = (e < EE) ? ei[EE + e] : (int)(e - EE);
    if (d >= wlo && d < whi) {
      int s = (e < EE) ? ei[e] : d;
      int p = atomicAdd(cur + d, 1);
      esrc[p] = s;
    }
  }
}

// ======================= layer-1 transform =======================
__global__ __launch_bounds__(256) void k_xform1(
    const float* __restrict__ x,
    const float* __restrict__ Wl, const float* __restrict__ bl,
    const float* __restrict__ Wr, const float* __restrict__ br,
    float* __restrict__ xl1, float* __restrict__ xr1) {
  __shared__ float Wlds[256 * 64];
  int tid = threadIdx.x;
  for (int i = tid; i < 256 * 64; i += 256) {
    int k = i >> 6, c = i & 63;
    Wlds[i] = (c < 32) ? Wl[k * 32 + c] : Wr[k * 32 + (c - 32)];
  }
  __syncthreads();
  int n = blockIdx.x * 16 + (tid >> 4);
  int cbase = (tid & 15) * 4;
  const float4* xrow = (const float4*)(x + (size_t)n * 256);
  float a0 = 0.f, a1 = 0.f, a2 = 0.f, a3 = 0.f;
#pragma unroll 4
  for (int k = 0; k < 256; k += 4) {
    float4 xv = xrow[k >> 2];
    const float* wr = &Wlds[k * 64 + cbase];
    float4 w0 = *(const float4*)(wr);
    float4 w1 = *(const float4*)(wr + 64);
    float4 w2 = *(const float4*)(wr + 128);
    float4 w3 = *(const float4*)(wr + 192);
    a0 += xv.x * w0.x + xv.y * w1.x + xv.z * w2.x + xv.w * w3.x;
    a1 += xv.x * w0.y + xv.y * w1.y + xv.z * w2.y + xv.w * w3.y;
    a2 += xv.x * w0.z + xv.y * w1.z + xv.z * w2.z + xv.w * w3.z;
    a3 += xv.x * w0.w + xv.y * w1.w + xv.z * w2.w + xv.w * w3.w;
  }
  if (cbase < 32) {
    float4 o = { a0 + bl[cbase], a1 + bl[cbase + 1], a2 + bl[cbase + 2], a3 + bl[cbase + 3] };
    *(float4*)(xl1 + (size_t)n * 32 + cbase) = o;
  } else {
    int c2 = cbase - 32;
    float4 o = { a0 + br[c2], a1 + br[c2 + 1], a2 + br[c2 + 2], a3 + br[c2 + 3] };
    *(float4*)(xr1 + (size_t)n * 32 + c2) = o;
  }
}

// ======================= layer-1 gather, unroll x4 =======================
__global__ __launch_bounds__(256) void k_gather1(
    const int* __restrict__ rp, const int* __restrict__ esrc,
    const float* __restrict__ xl1, const float* __restrict__ xr1,
    const float* __restrict__ att1, const float* __restrict__ bias1,
    float* __restrict__ h) {
  int n = blockIdx.x * 8 + (threadIdx.x >> 5);
  if (n >= NN) return;
  int l = threadIdx.x & 31;
  float av = att1[l];
  float xr = xr1[(size_t)n * 32 + l];
  int rpn = rp[n], dg = rp[n + 1] - rpn;
  float acc = 0.0f, den = 0.0f;
  int j = 0;
  for (; j + 4 <= dg; j += 4) {
    int s0 = esrc[rpn + j + 0];
    int s1 = esrc[rpn + j + 1];
    int s2 = esrc[rpn + j + 2];
    int s3 = esrc[rpn + j + 3];
    float x0 = xl1[(size_t)s0 * 32 + l];
    float x1 = xl1[(size_t)s1 * 32 + l];
    float x2 = xl1[(size_t)s2 * 32 + l];
    float x3 = xl1[(size_t)s3 * 32 + l];
    float p0 = lrelu(x0 + xr) * av;
    float p1 = lrelu(x1 + xr) * av;
    float p2 = lrelu(x2 + xr) * av;
    float p3 = lrelu(x3 + xr) * av;
    p0 += __shfl_xor(p0, 1); p1 += __shfl_xor(p1, 1);
    p2 += __shfl_xor(p2, 1); p3 += __shfl_xor(p3, 1);
    p0 += __shfl_xor(p0, 2); p1 += __shfl_xor(p1, 2);
    p2 += __shfl_xor(p2, 2); p3 += __shfl_xor(p3, 2);
    float w0 = __expf(p0), w1 = __expf(p1), w2 = __expf(p2), w3 = __expf(p3);
    den += w0 + w1 + w2 + w3;
    acc += w0 * x0 + w1 * x1 + w2 * x2 + w3 * x3;
  }
  for (; j < dg; ++j) {
    int s = esrc[rpn + j];
    float xl = xl1[(size_t)s * 32 + l];
    float p = lrelu(xl + xr) * av;
    p += __shfl_xor(p, 1);
    p += __shfl_xor(p, 2);
    float w = __expf(p);
    den += w;
    acc += w * xl;
  }
  float v = acc / (den + 1e-16f) + bias1[l];
  h[(size_t)n * 32 + l] = v > 0.0f ? v : expm1f(v);
}

// ======================= layer-2 transform =======================
__global__ __launch_bounds__(256) void k_xform2(
    const float* __restrict__ h,
    const float* __restrict__ Wl, const float* __restrict__ bl,
    const float* __restrict__ Wr, const float* __restrict__ br,
    float* __restrict__ hl2, float* __restrict__ hr2) {
  __shared__ float Wlds[32 * 128];
  int tid = threadIdx.x;
  for (int i = tid; i < 32 * 128; i += 256) {
    int k = i >> 7, c = i & 127;
    Wlds[i] = (c < 64) ? Wl[k * 64 + c] : Wr[k * 64 + (c - 64)];
  }
  __syncthreads();
  int n = blockIdx.x * 8 + (tid >> 5);
  int cbase = (tid & 31) * 4;
  const float4* hrow = (const float4*)(h + (size_t)n * 32);
  float a0 = 0.f, a1 = 0.f, a2 = 0.f, a3 = 0.f;
#pragma unroll
  for (int k = 0; k < 32; k += 4) {
    float4 xv = hrow[k >> 2];
    const float* wr = &Wlds[k * 128 + cbase];
    float4 w0 = *(const float4*)(wr);
    float4 w1 = *(const float4*)(wr + 128);
    float4 w2 = *(const float4*)(wr + 256);
    float4 w3 = *(const float4*)(wr + 384);
    a0 += xv.x * w0.x + xv.y * w1.x + xv.z * w2.x + xv.w * w3.x;
    a1 += xv.x * w0.y + xv.y * w1.y + xv.z * w2.y + xv.w * w3.y;
    a2 += xv.x * w0.z + xv.y * w1.z + xv.z * w2.z + xv.w * w3.z;
    a3 += xv.x * w0.w + xv.y * w1.w + xv.z * w2.w + xv.w * w3.w;
  }
  if (cbase < 64) {
    float4 o = { a0 + bl[cbase], a1 + bl[cbase + 1], a2 + bl[cbase + 2], a3 + bl[cbase + 3] };
    *(float4*)(hl2 + (size_t)n * 64 + cbase) = o;
  } else {
    int c2 = cbase - 64;
    float4 o = { a0 + br[c2], a1 + br[c2 + 1], a2 + br[c2 + 2], a3 + br[c2 + 3] };
    *(float4*)(hr2 + (size_t)n * 64 + c2) = o;
  }
}

// ======================= layer-2 gather (dense out), unroll x2 =======================
__global__ __launch_bounds__(256) void k_gather2(
    const int* __restrict__ rp, const int* __restrict__ esrc,
    const float* __restrict__ hl2, const float* __restrict__ hr2,
    const float* __restrict__ att2, const float* __restrict__ bias2,
    float* __restrict__ out2) {
  int n = (blockIdx.x * 256 + threadIdx.x) >> 3;
  if (n >= NN) return;
  int l8 = threadIdx.x & 7;
  float4 ac0 = *(const float4*)(att2 + l8 * 8);
  float4 ac1 = *(const float4*)(att2 + l8 * 8 + 4);
  float4 bs0 = *(const float4*)(bias2 + l8 * 8);
  float4 bs1 = *(const float4*)(bias2 + l8 * 8 + 4);
  const float4* hrp = (const float4*)(hr2 + (size_t)n * 64 + l8 * 8);
  float4 hr0 = hrp[0], hr1 = hrp[1];
  int rpn = rp[n], dg = rp[n + 1] - rpn;
  float4 a0 = {0,0,0,0}, a1 = {0,0,0,0};
  float den = 0.0f;
  int j = 0;
  for (; j + 2 <= dg; j += 2) {
    int s0 = esrc[rpn + j];
    int s1 = esrc[rpn + j + 1];
    const float4* hp0 = (const float4*)(hl2 + (size_t)s0 * 64 + l8 * 8);
    const float4* hp1 = (const float4*)(hl2 + (size_t)s1 * 64 + l8 * 8);
    float4 u0 = hp0[0], u1 = hp0[1];
    float4 v0 = hp1[0], v1 = hp1[1];
    float p0 = lrelu(u0.x + hr0.x) * ac0.x + lrelu(u0.y + hr0.y) * ac0.y
             + lrelu(u0.z + hr0.z) * ac0.z + lrelu(u0.w + hr0.w) * ac0.w
             + lrelu(u1.x + hr1.x) * ac1.x + lrelu(u1.y + hr1.y) * ac1.y
             + lrelu(u1.z + hr1.z) * ac1.z + lrelu(u1.w + hr1.w) * ac1.w;
    float p1 = lrelu(v0.x + hr0.x) * ac0.x + lrelu(v0.y + hr0.y) * ac0.y
             + lrelu(v0.z + hr0.z) * ac0.z + lrelu(v0.w + hr0.w) * ac0.w
             + lrelu(v1.x + hr1.x) * ac1.x + lrelu(v1.y + hr1.y) * ac1.y
             + lrelu(v1.z + hr1.z) * ac1.z + lrelu(v1.w + hr1.w) * ac1.w;
    p0 += __shfl_xor(p0, 1); p1 += __shfl_xor(p1, 1);
    p0 += __shfl_xor(p0, 2); p1 += __shfl_xor(p1, 2);
    p0 += __shfl_xor(p0, 4); p1 += __shfl_xor(p1, 4);
    float w0 = __expf(p0), w1 = __expf(p1);
    den += w0 + w1;
    a0.x += w0 * u0.x + w1 * v0.x; a0.y += w0 * u0.y + w1 * v0.y;
    a0.z += w0 * u0.z + w1 * v0.z; a0.w += w0 * u0.w + w1 * v0.w;
    a1.x += w0 * u1.x + w1 * v1.x; a1.y += w0 * u1.y + w1 * v1.y;
    a1.z += w0 * u1.z + w1 * v1.z; a1.w += w0 * u1.w + w1 * v1.w;
  }
  for (; j < dg; ++j) {
    int s = esrc[rpn + j];
    const float4* hp = (const float4*)(hl2 + (size_t)s * 64 + l8 * 8);
    float4 u0 = hp[0], u1 = hp[1];
    float p = lrelu(u0.x + hr0.x) * ac0.x + lrelu(u0.y + hr0.y) * ac0.y
            + lrelu(u0.z + hr0.z) * ac0.z + lrelu(u0.w + hr0.w) * ac0.w
            + lrelu(u1.x + hr1.x) * ac1.x + lrelu(u1.y + hr1.y) * ac1.y
            + lrelu(u1.z + hr1.z) * ac1.z + lrelu(u1.w + hr1.w) * ac1.w;
    p += __shfl_xor(p, 1);
    p += __shfl_xor(p, 2);
    p += __shfl_xor(p, 4);
    float w = __expf(p);
    den += w;
    a0.x += w * u0.x; a0.y += w * u0.y; a0.z += w * u0.z; a0.w += w * u0.w;
    a1.x += w * u1.x; a1.y += w * u1.y; a1.z += w * u1.z; a1.w += w * u1.w;
  }
  float inv = 1.0f / (den + 1e-16f);
  float4 o0 = { a0.x * inv + bs0.x, a0.y * inv + bs0.y, a0.z * inv + bs0.z, a0.w * inv + bs0.w };
  float4 o1 = { a1.x * inv + bs1.x, a1.y * inv + bs1.y, a1.z * inv + bs1.z, a1.w * inv + bs1.w };
  float4* op = (float4*)(out2 + (size_t)n * 64 + l8 * 8);
  op[0] = o0; op[1] = o1;
}

// ======================= pooling =======================
__global__ __launch_bounds__(256) void k_pool(
    const float* __restrict__ out2, const int* __restrict__ batch,
    float* __restrict__ ppart) {
  __shared__ float ssum[NG * 64];
  __shared__ float scnt[NG];
  int tid = threadIdx.x;
  for (int i = tid; i < NG * 64; i += 256) ssum[i] = 0.0f;
  if (tid < NG) scnt[tid] = 0.0f;
  __syncthreads();
  int total = NN * 64;
  for (int idx = blockIdx.x * 256 + tid; idx < total; idx += gridDim.x * 256) {
    int n = idx >> 6, c = idx & 63;
    int g = batch[n];
    atomicAdd(&ssum[g * 64 + c], out2[idx]);
    if (c == 0) atomicAdd(&scnt[g], 1.0f);
  }
  __syncthreads();
  float* pb = ppart + (size_t)blockIdx.x * (NG * 64 + NG);
  for (int i = tid; i < NG * 64; i += 256) pb[i] = ssum[i];
  if (tid < NG) pb[NG * 64 + tid] = scnt[tid];
}

__global__ __launch_bounds__(256) void k_final(
    const float* __restrict__ ppart, float* __restrict__ out) {
  int i = blockIdx.x * 256 + threadIdx.x;
  if (i >= NG * 64) return;
  int g = i >> 6;
  float s = 0.0f, c = 0.0f;
  for (int b = 0; b < NPB; ++b) {
    const float* pb = ppart + (size_t)b * (NG * 64 + NG);
    s += pb[i];
    c += pb[NG * 64 + g];
  }
  out[i] = s / fmaxf(c, 1.0f);
}

extern "C" void kernel_launch(void* const* d_in, const int* in_sizes, int n_in,
                              void* d_out, int out_size, void* d_ws, size_t ws_size,
                              hipStream_t stream) {
  const float* x     = (const float*)d_in[0];
  const int*   ei    = (const int*)d_in[1];
  const int*   batch = (const int*)d_in[2];
  const float* W1l   = (const float*)d_in[3];
  const float* b1l   = (const float*)d_in[4];
  const float* W1r   = (const float*)d_in[5];
  const float* b1r   = (const float*)d_in[6];
  const float* att1  = (const float*)d_in[7];
  const float* bias1 = (const float*)d_in[8];
  const float* W2l   = (const float*)d_in[9];
  const float* b2l   = (const float*)d_in[10];
  const float* W2r   = (const float*)d_in[11];
  const float* b2r   = (const float*)d_in[12];
  const float* att2  = (const float*)d_in[13];
  const float* bias2 = (const float*)d_in[14];
  float* ws = (float*)d_ws;
  int*   wi = (int*)d_ws;
  float* out = (float*)d_out;

  hipMemsetAsync(wi + OFF_DEG, 0, 100096 * 4, stream);

  // CSR build: count + scan + windowed multi-pass scatter
  k_count<<<2048, 256, 0, stream>>>(ei, wi + OFF_DEG);
  k_scan1<<<NBLK, 256, 0, stream>>>(wi + OFF_DEG, wi + OFF_TMP, wi + OFF_PART);
  k_scan2<<<1, 512, 0, stream>>>(wi + OFF_PART);
  k_scan3<<<NBLK, 256, 0, stream>>>(wi + OFF_DEG, wi + OFF_TMP, wi + OFF_PART,
                                    wi + OFF_RP, wi + OFF_CUR);
  k_scatterw<<<SC_P * SC_BPP, 256, 0, stream>>>(ei, wi + OFF_CUR, wi + OFF_ESRC);

  // layer 1
  k_xform1<<<NN / 16, 256, 0, stream>>>(x, W1l, b1l, W1r, b1r, ws + OFF_XL1, ws + OFF_XR1);
  k_gather1<<<NN / 8, 256, 0, stream>>>(wi + OFF_RP, wi + OFF_ESRC,
                                        ws + OFF_XL1, ws + OFF_XR1, att1, bias1, ws + OFF_H);
  // layer 2
  k_xform2<<<NN / 8, 256, 0, stream>>>(ws + OFF_H, W2l, b2l, W2r, b2r,
                                       ws + OFF_HL2, ws + OFF_HR2);
  k_gather2<<<(NN * 8 + 255) / 256, 256, 0, stream>>>(wi + OFF_RP, wi + OFF_ESRC,
                                                      ws + OFF_HL2, ws + OFF_HR2, att2, bias2,
                                                      ws + OFF_OUT2);
  k_pool<<<NPB, 256, 0, stream>>>(ws + OFF_OUT2, batch, ws + OFF_PPART);
  k_final<<<16, 256, 0, stream>>>(ws + OFF_PPART, out);
}

// Round 6
// 540.840 us; speedup vs baseline: 1.4632x; 1.4632x over previous
//
#include <hip/hip_runtime.h>
#include <math.h>

#define NN 100000
#define EE 3200000
#define ET (EE + NN)
#define NG 64
#define NPB 128        // pool partial blocks

// bucket sort params
#define NB 196         // ceil(NN/512) buckets
#define BWID 512       // nodes per bucket (dst >> 9)
#define PCHUNK 8192    // edges per partition block
#define PBLOCKS ((ET + PCHUNK - 1) / PCHUNK)

// workspace layout (4-byte units)
#define OFF_XL1   0u
#define OFF_XR1   3200000u
#define OFF_H     6400000u
#define OFF_HL2   9600000u
#define OFF_HR2   16000000u
#define OFF_OUT2  0u           /* reuses XL1/XR1 (dead after layer 1) */
#define OFF_BEDGE 9600000u     /* int2[ET] aliases HL2/HR2 (dead until xform2) */
#define OFF_PPART 22400000u    /* NPB * 4160 */
#define OFF_RP    22932480u    /* NN+1 */
#define OFF_ESRC  23032488u    /* ET */
#define OFF_BCNT  26332488u
#define OFF_BOFF  26332688u
#define OFF_GCUR  26332888u
#define WS_UNITS  26333088u

__device__ __forceinline__ float lrelu(float v) { return v > 0.0f ? v : 0.2f * v; }

// ======================= bucket counting sort: CSR build =======================
__global__ __launch_bounds__(256) void k_bcount(const int* __restrict__ ei,
                                                int* __restrict__ bcnt) {
  __shared__ int h[NB];
  for (int i = threadIdx.x; i < NB; i += 256) h[i] = 0;
  __syncthreads();
  for (long e = (long)blockIdx.x * 256 + threadIdx.x; e < ET; e += (long)gridDim.x * 256) {
    int d = (e < EE) ? ei[EE + e] : (int)(e - EE);
    atomicAdd(&h[d >> 9], 1);
  }
  __syncthreads();
  for (int i = threadIdx.x; i < NB; i += 256) if (h[i]) atomicAdd(&bcnt[i], h[i]);
}

__global__ __launch_bounds__(256) void k_bscan(const int* __restrict__ bcnt,
                                               int* __restrict__ boff, int* __restrict__ gcur) {
  __shared__ int sd[256];
  int t = threadIdx.x;
  int v = (t < NB) ? bcnt[t] : 0;
  sd[t] = v;
  __syncthreads();
  for (int o = 1; o < 256; o <<= 1) {
    int u = (t >= o) ? sd[t - o] : 0;
    __syncthreads();
    sd[t] += u;
    __syncthreads();
  }
  if (t < NB) { boff[t] = sd[t] - v; gcur[t] = sd[t] - v; }
  if (t == 0) boff[NB] = ET;
}

// LDS-reorder partition: 8192 edges/block -> bucket-grouped in LDS -> dense
// contiguous writes into per-bucket global regions (no serial flush loops).
__global__ __launch_bounds__(512) void k_part(const int* __restrict__ ei,
                                              int* __restrict__ gcur,
                                              int2* __restrict__ bedge) {
  __shared__ int  cnt[NB];    // count, then reused as placement cursor
  __shared__ int  lbase[NB];  // local exclusive scan base
  __shared__ int  gbase[NB];  // reserved global base
  __shared__ int  sc[256];    // scan scratch
  __shared__ int2 buf[PCHUNK];
  int tid = threadIdx.x;
  long e0 = (long)blockIdx.x * PCHUNK;
  int nedge = (e0 + PCHUNK <= ET) ? PCHUNK : (int)(ET - e0);

  for (int i = tid; i < NB; i += 512) cnt[i] = 0;
  __syncthreads();
  // pass 1: histogram
  for (int i = tid; i < nedge; i += 512) {
    long e = e0 + i;
    int d = (e < EE) ? ei[EE + e] : (int)(e - EE);
    atomicAdd(&cnt[d >> 9], 1);
  }
  __syncthreads();
  // scan NB counters (inclusive over padded 256, then convert)
  if (tid < 256) sc[tid] = (tid < NB) ? cnt[tid] : 0;
  __syncthreads();
  for (int o = 1; o < 256; o <<= 1) {
    int u = (tid < 256 && tid >= o) ? sc[tid - o] : 0;
    __syncthreads();
    if (tid < 256) sc[tid] += u;
    __syncthreads();
  }
  if (tid < NB) lbase[tid] = sc[tid] - cnt[tid];
  __syncthreads();
  // reserve global space, reset cursors
  if (tid < NB) {
    int c = cnt[tid];
    gbase[tid] = c ? atomicAdd(&gcur[tid], c) : 0;
    cnt[tid] = 0;
  }
  __syncthreads();
  // pass 2: place edges into LDS grouped by bucket
  for (int i = tid; i < nedge; i += 512) {
    long e = e0 + i;
    int s, d;
    if (e < EE) { s = ei[e]; d = ei[EE + e]; }
    else { s = (int)(e - EE); d = s; }
    int b = d >> 9;
    int r = atomicAdd(&cnt[b], 1);
    buf[lbase[b] + r] = make_int2(s, d);
  }
  __syncthreads();
  // output: linear sweep -> contiguous runs per bucket
  for (int i = tid; i < nedge; i += 512) {
    int2 ed = buf[i];
    int b = ed.y >> 9;
    bedge[gbase[b] + (i - lbase[b])] = ed;
  }
}

// per-bucket: LDS node-degree count + scan -> rp; LDS cursors -> esrc
__global__ __launch_bounds__(512) void k_csr(const int* __restrict__ boff,
                                             const int2* __restrict__ bedge,
                                             int* __restrict__ rp, int* __restrict__ esrc) {
  __shared__ int sdeg[BWID];
  __shared__ int sscan[BWID];
  int b = blockIdx.x, t = threadIdx.x;
  int n0 = b * BWID;
  int lo = boff[b], hi = boff[b + 1];
  sdeg[t] = 0;
  __syncthreads();
  for (int i = lo + t; i < hi; i += 512) {
    int2 ed = bedge[i];
    atomicAdd(&sdeg[ed.y - n0], 1);
  }
  __syncthreads();
  int v = sdeg[t];
  sscan[t] = v;
  __syncthreads();
  for (int o = 1; o < 512; o <<= 1) {
    int u = (t >= o) ? sscan[t - o] : 0;
    __syncthreads();
    sscan[t] += u;
    __syncthreads();
  }
  int excl = sscan[t] - v;
  int n = n0 + t;
  if (n < NN) rp[n] = lo + excl;
  if (b == NB - 1 && t == 0) rp[NN] = ET;
  __syncthreads();
  sdeg[t] = lo + excl;   // reuse as cursor
  __syncthreads();
  for (int i = lo + t; i < hi; i += 512) {
    int2 ed = bedge[i];
    int p = atomicAdd(&sdeg[ed.y - n0], 1);
    esrc[p] = ed.x;
  }
}

// ======================= layer-1 transform =======================
__global__ __launch_bounds__(256) void k_xform1(
    const float* __restrict__ x,
    const float* __restrict__ Wl, const float* __restrict__ bl,
    const float* __restrict__ Wr, const float* __restrict__ br,
    float* __restrict__ xl1, float* __restrict__ xr1) {
  __shared__ float Wlds[256 * 64];
  int tid = threadIdx.x;
  for (int i = tid; i < 256 * 64; i += 256) {
    int k = i >> 6, c = i & 63;
    Wlds[i] = (c < 32) ? Wl[k * 32 + c] : Wr[k * 32 + (c - 32)];
  }
  __syncthreads();
  int n = blockIdx.x * 16 + (tid >> 4);
  int cbase = (tid & 15) * 4;
  const float4* xrow = (const float4*)(x + (size_t)n * 256);
  float a0 = 0.f, a1 = 0.f, a2 = 0.f, a3 = 0.f;
#pragma unroll 4
  for (int k = 0; k < 256; k += 4) {
    float4 xv = xrow[k >> 2];
    const float* wr = &Wlds[k * 64 + cbase];
    float4 w0 = *(const float4*)(wr);
    float4 w1 = *(const float4*)(wr + 64);
    float4 w2 = *(const float4*)(wr + 128);
    float4 w3 = *(const float4*)(wr + 192);
    a0 += xv.x * w0.x + xv.y * w1.x + xv.z * w2.x + xv.w * w3.x;
    a1 += xv.x * w0.y + xv.y * w1.y + xv.z * w2.y + xv.w * w3.y;
    a2 += xv.x * w0.z + xv.y * w1.z + xv.z * w2.z + xv.w * w3.z;
    a3 += xv.x * w0.w + xv.y * w1.w + xv.z * w2.w + xv.w * w3.w;
  }
  if (cbase < 32) {
    float4 o = { a0 + bl[cbase], a1 + bl[cbase + 1], a2 + bl[cbase + 2], a3 + bl[cbase + 3] };
    *(float4*)(xl1 + (size_t)n * 32 + cbase) = o;
  } else {
    int c2 = cbase - 32;
    float4 o = { a0 + br[c2], a1 + br[c2 + 1], a2 + br[c2 + 2], a3 + br[c2 + 3] };
    *(float4*)(xr1 + (size_t)n * 32 + c2) = o;
  }
}

// ======================= layer-1 gather, unroll x4 =======================
__global__ __launch_bounds__(256) void k_gather1(
    const int* __restrict__ rp, const int* __restrict__ esrc,
    const float* __restrict__ xl1, const float* __restrict__ xr1,
    const float* __restrict__ att1, const float* __restrict__ bias1,
    float* __restrict__ h) {
  int n = blockIdx.x * 8 + (threadIdx.x >> 5);
  if (n >= NN) return;
  int l = threadIdx.x & 31;
  float av = att1[l];
  float xr = xr1[(size_t)n * 32 + l];
  int rpn = rp[n], dg = rp[n + 1] - rpn;
  float acc = 0.0f, den = 0.0f;
  int j = 0;
  for (; j + 4 <= dg; j += 4) {
    int s0 = esrc[rpn + j + 0];
    int s1 = esrc[rpn + j + 1];
    int s2 = esrc[rpn + j + 2];
    int s3 = esrc[rpn + j + 3];
    float x0 = xl1[(size_t)s0 * 32 + l];
    float x1 = xl1[(size_t)s1 * 32 + l];
    float x2 = xl1[(size_t)s2 * 32 + l];
    float x3 = xl1[(size_t)s3 * 32 + l];
    float p0 = lrelu(x0 + xr) * av;
    float p1 = lrelu(x1 + xr) * av;
    float p2 = lrelu(x2 + xr) * av;
    float p3 = lrelu(x3 + xr) * av;
    p0 += __shfl_xor(p0, 1); p1 += __shfl_xor(p1, 1);
    p2 += __shfl_xor(p2, 1); p3 += __shfl_xor(p3, 1);
    p0 += __shfl_xor(p0, 2); p1 += __shfl_xor(p1, 2);
    p2 += __shfl_xor(p2, 2); p3 += __shfl_xor(p3, 2);
    float w0 = __expf(p0), w1 = __expf(p1), w2 = __expf(p2), w3 = __expf(p3);
    den += w0 + w1 + w2 + w3;
    acc += w0 * x0 + w1 * x1 + w2 * x2 + w3 * x3;
  }
  for (; j < dg; ++j) {
    int s = esrc[rpn + j];
    float xl = xl1[(size_t)s * 32 + l];
    float p = lrelu(xl + xr) * av;
    p += __shfl_xor(p, 1);
    p += __shfl_xor(p, 2);
    float w = __expf(p);
    den += w;
    acc += w * xl;
  }
  float v = acc / (den + 1e-16f) + bias1[l];
  h[(size_t)n * 32 + l] = v > 0.0f ? v : expm1f(v);
}

// ======================= layer-2 transform =======================
__global__ __launch_bounds__(256) void k_xform2(
    const float* __restrict__ h,
    const float* __restrict__ Wl, const float* __restrict__ bl,
    const float* __restrict__ Wr, const float* __restrict__ br,
    float* __restrict__ hl2, float* __restrict__ hr2) {
  __shared__ float Wlds[32 * 128];
  int tid = threadIdx.x;
  for (int i = tid; i < 32 * 128; i += 256) {
    int k = i >> 7, c = i & 127;
    Wlds[i] = (c < 64) ? Wl[k * 64 + c] : Wr[k * 64 + (c - 64)];
  }
  __syncthreads();
  int n = blockIdx.x * 8 + (tid >> 5);
  int cbase = (tid & 31) * 4;
  const float4* hrow = (const float4*)(h + (size_t)n * 32);
  float a0 = 0.f, a1 = 0.f, a2 = 0.f, a3 = 0.f;
#pragma unroll
  for (int k = 0; k < 32; k += 4) {
    float4 xv = hrow[k >> 2];
    const float* wr = &Wlds[k * 128 + cbase];
    float4 w0 = *(const float4*)(wr);
    float4 w1 = *(const float4*)(wr + 128);
    float4 w2 = *(const float4*)(wr + 256);
    float4 w3 = *(const float4*)(wr + 384);
    a0 += xv.x * w0.x + xv.y * w1.x + xv.z * w2.x + xv.w * w3.x;
    a1 += xv.x * w0.y + xv.y * w1.y + xv.z * w2.y + xv.w * w3.y;
    a2 += xv.x * w0.z + xv.y * w1.z + xv.z * w2.z + xv.w * w3.z;
    a3 += xv.x * w0.w + xv.y * w1.w + xv.z * w2.w + xv.w * w3.w;
  }
  if (cbase < 64) {
    float4 o = { a0 + bl[cbase], a1 + bl[cbase + 1], a2 + bl[cbase + 2], a3 + bl[cbase + 3] };
    *(float4*)(hl2 + (size_t)n * 64 + cbase) = o;
  } else {
    int c2 = cbase - 64;
    float4 o = { a0 + br[c2], a1 + br[c2 + 1], a2 + br[c2 + 2], a3 + br[c2 + 3] };
    *(float4*)(hr2 + (size_t)n * 64 + c2) = o;
  }
}

// ======================= layer-2 gather (dense out), unroll x2 =======================
__global__ __launch_bounds__(256) void k_gather2(
    const int* __restrict__ rp, const int* __restrict__ esrc,
    const float* __restrict__ hl2, const float* __restrict__ hr2,
    const float* __restrict__ att2, const float* __restrict__ bias2,
    float* __restrict__ out2) {
  int n = (blockIdx.x * 256 + threadIdx.x) >> 3;
  if (n >= NN) return;
  int l8 = threadIdx.x & 7;
  float4 ac0 = *(const float4*)(att2 + l8 * 8);
  float4 ac1 = *(const float4*)(att2 + l8 * 8 + 4);
  float4 bs0 = *(const float4*)(bias2 + l8 * 8);
  float4 bs1 = *(const float4*)(bias2 + l8 * 8 + 4);
  const float4* hrp = (const float4*)(hr2 + (size_t)n * 64 + l8 * 8);
  float4 hr0 = hrp[0], hr1 = hrp[1];
  int rpn = rp[n], dg = rp[n + 1] - rpn;
  float4 a0 = {0,0,0,0}, a1 = {0,0,0,0};
  float den = 0.0f;
  int j = 0;
  for (; j + 2 <= dg; j += 2) {
    int s0 = esrc[rpn + j];
    int s1 = esrc[rpn + j + 1];
    const float4* hp0 = (const float4*)(hl2 + (size_t)s0 * 64 + l8 * 8);
    const float4* hp1 = (const float4*)(hl2 + (size_t)s1 * 64 + l8 * 8);
    float4 u0 = hp0[0], u1 = hp0[1];
    float4 v0 = hp1[0], v1 = hp1[1];
    float p0 = lrelu(u0.x + hr0.x) * ac0.x + lrelu(u0.y + hr0.y) * ac0.y
             + lrelu(u0.z + hr0.z) * ac0.z + lrelu(u0.w + hr0.w) * ac0.w
             + lrelu(u1.x + hr1.x) * ac1.x + lrelu(u1.y + hr1.y) * ac1.y
             + lrelu(u1.z + hr1.z) * ac1.z + lrelu(u1.w + hr1.w) * ac1.w;
    float p1 = lrelu(v0.x + hr0.x) * ac0.x + lrelu(v0.y + hr0.y) * ac0.y
             + lrelu(v0.z + hr0.z) * ac0.z + lrelu(v0.w + hr0.w) * ac0.w
             + lrelu(v1.x + hr1.x) * ac1.x + lrelu(v1.y + hr1.y) * ac1.y
             + lrelu(v1.z + hr1.z) * ac1.z + lrelu(v1.w + hr1.w) * ac1.w;
    p0 += __shfl_xor(p0, 1); p1 += __shfl_xor(p1, 1);
    p0 += __shfl_xor(p0, 2); p1 += __shfl_xor(p1, 2);
    p0 += __shfl_xor(p0, 4); p1 += __shfl_xor(p1, 4);
    float w0 = __expf(p0), w1 = __expf(p1);
    den += w0 + w1;
    a0.x += w0 * u0.x + w1 * v0.x; a0.y += w0 * u0.y + w1 * v0.y;
    a0.z += w0 * u0.z + w1 * v0.z; a0.w += w0 * u0.w + w1 * v0.w;
    a1.x += w0 * u1.x + w1 * v1.x; a1.y += w0 * u1.y + w1 * v1.y;
    a1.z += w0 * u1.z + w1 * v1.z; a1.w += w0 * u1.w + w1 * v1.w;
  }
  for (; j < dg; ++j) {
    int s = esrc[rpn + j];
    const float4* hp = (const float4*)(hl2 + (size_t)s * 64 + l8 * 8);
    float4 u0 = hp[0], u1 = hp[1];
    float p = lrelu(u0.x + hr0.x) * ac0.x + lrelu(u0.y + hr0.y) * ac0.y
            + lrelu(u0.z + hr0.z) * ac0.z + lrelu(u0.w + hr0.w) * ac0.w
            + lrelu(u1.x + hr1.x) * ac1.x + lrelu(u1.y + hr1.y) * ac1.y
            + lrelu(u1.z + hr1.z) * ac1.z + lrelu(u1.w + hr1.w) * ac1.w;
    p += __shfl_xor(p, 1);
    p += __shfl_xor(p, 2);
    p += __shfl_xor(p, 4);
    float w = __expf(p);
    den += w;
    a0.x += w * u0.x; a0.y += w * u0.y; a0.z += w * u0.z; a0.w += w * u0.w;
    a1.x += w * u1.x; a1.y += w * u1.y; a1.z += w * u1.z; a1.w += w * u1.w;
  }
  float inv = 1.0f / (den + 1e-16f);
  float4 o0 = { a0.x * inv + bs0.x, a0.y * inv + bs0.y, a0.z * inv + bs0.z, a0.w * inv + bs0.w };
  float4 o1 = { a1.x * inv + bs1.x, a1.y * inv + bs1.y, a1.z * inv + bs1.z, a1.w * inv + bs1.w };
  float4* op = (float4*)(out2 + (size_t)n * 64 + l8 * 8);
  op[0] = o0; op[1] = o1;
}

// ======================= pooling =======================
__global__ __launch_bounds__(256) void k_pool(
    const float* __restrict__ out2, const int* __restrict__ batch,
    float* __restrict__ ppart) {
  __shared__ float ssum[NG * 64];
  __shared__ float scnt[NG];
  int tid = threadIdx.x;
  for (int i = tid; i < NG * 64; i += 256) ssum[i] = 0.0f;
  if (tid < NG) scnt[tid] = 0.0f;
  __syncthreads();
  int total = NN * 64;
  for (int idx = blockIdx.x * 256 + tid; idx < total; idx += gridDim.x * 256) {
    int n = idx >> 6, c = idx & 63;
    int g = batch[n];
    atomicAdd(&ssum[g * 64 + c], out2[idx]);
    if (c == 0) atomicAdd(&scnt[g], 1.0f);
  }
  __syncthreads();
  float* pb = ppart + (size_t)blockIdx.x * (NG * 64 + NG);
  for (int i = tid; i < NG * 64; i += 256) pb[i] = ssum[i];
  if (tid < NG) pb[NG * 64 + tid] = scnt[tid];
}

__global__ __launch_bounds__(256) void k_final(
    const float* __restrict__ ppart, float* __restrict__ out) {
  int i = blockIdx.x * 256 + threadIdx.x;
  if (i >= NG * 64) return;
  int g = i >> 6;
  float s = 0.0f, c = 0.0f;
  for (int b = 0; b < NPB; ++b) {
    const float* pb = ppart + (size_t)b * (NG * 64 + NG);
    s += pb[i];
    c += pb[NG * 64 + g];
  }
  out[i] = s / fmaxf(c, 1.0f);
}

extern "C" void kernel_launch(void* const* d_in, const int* in_sizes, int n_in,
                              void* d_out, int out_size, void* d_ws, size_t ws_size,
                              hipStream_t stream) {
  const float* x     = (const float*)d_in[0];
  const int*   ei    = (const int*)d_in[1];
  const int*   batch = (const int*)d_in[2];
  const float* W1l   = (const float*)d_in[3];
  const float* b1l   = (const float*)d_in[4];
  const float* W1r   = (const float*)d_in[5];
  const float* b1r   = (const float*)d_in[6];
  const float* att1  = (const float*)d_in[7];
  const float* bias1 = (const float*)d_in[8];
  const float* W2l   = (const float*)d_in[9];
  const float* b2l   = (const float*)d_in[10];
  const float* W2r   = (const float*)d_in[11];
  const float* b2r   = (const float*)d_in[12];
  const float* att2  = (const float*)d_in[13];
  const float* bias2 = (const float*)d_in[14];
  float* ws = (float*)d_ws;
  int*   wi = (int*)d_ws;
  float* out = (float*)d_out;

  hipMemsetAsync(wi + OFF_BCNT, 0, NB * 4, stream);

  // CSR build via bucket counting sort (LDS-reorder partition)
  k_bcount<<<512, 256, 0, stream>>>(ei, wi + OFF_BCNT);
  k_bscan<<<1, 256, 0, stream>>>(wi + OFF_BCNT, wi + OFF_BOFF, wi + OFF_GCUR);
  k_part<<<PBLOCKS, 512, 0, stream>>>(ei, wi + OFF_GCUR, (int2*)(wi + OFF_BEDGE));
  k_csr<<<NB, 512, 0, stream>>>(wi + OFF_BOFF, (const int2*)(wi + OFF_BEDGE),
                                wi + OFF_RP, wi + OFF_ESRC);

  // layer 1
  k_xform1<<<NN / 16, 256, 0, stream>>>(x, W1l, b1l, W1r, b1r, ws + OFF_XL1, ws + OFF_XR1);
  k_gather1<<<NN / 8, 256, 0, stream>>>(wi + OFF_RP, wi + OFF_ESRC,
                                        ws + OFF_XL1, ws + OFF_XR1, att1, bias1, ws + OFF_H);
  // layer 2 (xform2 overwrites bedge region — bedge is dead by then)
  k_xform2<<<NN / 8, 256, 0, stream>>>(ws + OFF_H, W2l, b2l, W2r, b2r,
                                       ws + OFF_HL2, ws + OFF_HR2);
  k_gather2<<<(NN * 8 + 255) / 256, 256, 0, stream>>>(wi + OFF_RP, wi + OFF_ESRC,
                                                      ws + OFF_HL2, ws + OFF_HR2, att2, bias2,
                                                      ws + OFF_OUT2);
  k_pool<<<NPB, 256, 0, stream>>>(ws + OFF_OUT2, batch, ws + OFF_PPART);
  k_final<<<16, 256, 0, stream>>>(ws + OFF_PPART, out);
}

// Round 7
// 484.252 us; speedup vs baseline: 1.6342x; 1.1169x over previous
//
#include <hip/hip_runtime.h>
#include <math.h>

#define NN 100000
#define EE 3200000
#define ET (EE + NN)
#define NG 64
#define NPB 128        // pool partial blocks

// bucket sort params
#define NB 196         // ceil(NN/512) buckets
#define BWID 512       // nodes per bucket (dst >> 9)
#define PCHUNK 8192    // edges per partition block
#define PBLOCKS ((ET + PCHUNK - 1) / PCHUNK)

// workspace layout (4-byte units)
#define OFF_XL1   0u
#define OFF_XR1   3200000u
#define OFF_H     6400000u
#define OFF_HL2   9600000u
#define OFF_HR2   16000000u
#define OFF_OUT2  0u           /* reuses XL1/XR1 (dead after layer 1) */
#define OFF_BEDGE 9600000u     /* int2[ET] aliases HL2/HR2 (dead until xform2) */
#define OFF_PPART 22400000u    /* NPB * 4160 */
#define OFF_RP    22932480u    /* NN+1 */
#define OFF_ESRC  23032488u    /* ET */
#define OFF_BCNT  26332488u
#define OFF_BOFF  26332688u
#define OFF_GCUR  26332888u
#define WS_UNITS  26333088u

__device__ __forceinline__ float lrelu(float v) { return v > 0.0f ? v : 0.2f * v; }

// ======================= bucket counting sort: CSR build =======================
__global__ __launch_bounds__(256) void k_bcount(const int* __restrict__ ei,
                                                int* __restrict__ bcnt) {
  __shared__ int h[NB];
  for (int i = threadIdx.x; i < NB; i += 256) h[i] = 0;
  __syncthreads();
  for (long e = (long)blockIdx.x * 256 + threadIdx.x; e < ET; e += (long)gridDim.x * 256) {
    int d = (e < EE) ? ei[EE + e] : (int)(e - EE);
    atomicAdd(&h[d >> 9], 1);
  }
  __syncthreads();
  for (int i = threadIdx.x; i < NB; i += 256) if (h[i]) atomicAdd(&bcnt[i], h[i]);
}

__global__ __launch_bounds__(256) void k_bscan(const int* __restrict__ bcnt,
                                               int* __restrict__ boff, int* __restrict__ gcur) {
  __shared__ int sd[256];
  int t = threadIdx.x;
  int v = (t < NB) ? bcnt[t] : 0;
  sd[t] = v;
  __syncthreads();
  for (int o = 1; o < 256; o <<= 1) {
    int u = (t >= o) ? sd[t - o] : 0;
    __syncthreads();
    sd[t] += u;
    __syncthreads();
  }
  if (t < NB) { boff[t] = sd[t] - v; gcur[t] = sd[t] - v; }
  if (t == 0) boff[NB] = ET;
}

// LDS-reorder partition: 8192 edges/block -> bucket-grouped in LDS -> dense writes
__global__ __launch_bounds__(512) void k_part(const int* __restrict__ ei,
                                              int* __restrict__ gcur,
                                              int2* __restrict__ bedge) {
  __shared__ int  cnt[NB];
  __shared__ int  lbase[NB];
  __shared__ int  gbase[NB];
  __shared__ int  sc[256];
  __shared__ int2 buf[PCHUNK];
  int tid = threadIdx.x;
  long e0 = (long)blockIdx.x * PCHUNK;
  int nedge = (e0 + PCHUNK <= ET) ? PCHUNK : (int)(ET - e0);

  for (int i = tid; i < NB; i += 512) cnt[i] = 0;
  __syncthreads();
  for (int i = tid; i < nedge; i += 512) {
    long e = e0 + i;
    int d = (e < EE) ? ei[EE + e] : (int)(e - EE);
    atomicAdd(&cnt[d >> 9], 1);
  }
  __syncthreads();
  if (tid < 256) sc[tid] = (tid < NB) ? cnt[tid] : 0;
  __syncthreads();
  for (int o = 1; o < 256; o <<= 1) {
    int u = (tid < 256 && tid >= o) ? sc[tid - o] : 0;
    __syncthreads();
    if (tid < 256) sc[tid] += u;
    __syncthreads();
  }
  if (tid < NB) lbase[tid] = sc[tid] - cnt[tid];
  __syncthreads();
  if (tid < NB) {
    int c = cnt[tid];
    gbase[tid] = c ? atomicAdd(&gcur[tid], c) : 0;
    cnt[tid] = 0;
  }
  __syncthreads();
  for (int i = tid; i < nedge; i += 512) {
    long e = e0 + i;
    int s, d;
    if (e < EE) { s = ei[e]; d = ei[EE + e]; }
    else { s = (int)(e - EE); d = s; }
    int b = d >> 9;
    int r = atomicAdd(&cnt[b], 1);
    buf[lbase[b] + r] = make_int2(s, d);
  }
  __syncthreads();
  for (int i = tid; i < nedge; i += 512) {
    int2 ed = buf[i];
    int b = ed.y >> 9;
    bedge[gbase[b] + (i - lbase[b])] = ed;
  }
}

// per-bucket: LDS node-degree count + scan -> rp; LDS cursors -> esrc
__global__ __launch_bounds__(512) void k_csr(const int* __restrict__ boff,
                                             const int2* __restrict__ bedge,
                                             int* __restrict__ rp, int* __restrict__ esrc) {
  __shared__ int sdeg[BWID];
  __shared__ int sscan[BWID];
  int b = blockIdx.x, t = threadIdx.x;
  int n0 = b * BWID;
  int lo = boff[b], hi = boff[b + 1];
  sdeg[t] = 0;
  __syncthreads();
  for (int i = lo + t; i < hi; i += 512) {
    int2 ed = bedge[i];
    atomicAdd(&sdeg[ed.y - n0], 1);
  }
  __syncthreads();
  int v = sdeg[t];
  sscan[t] = v;
  __syncthreads();
  for (int o = 1; o < 512; o <<= 1) {
    int u = (t >= o) ? sscan[t - o] : 0;
    __syncthreads();
    sscan[t] += u;
    __syncthreads();
  }
  int excl = sscan[t] - v;
  int n = n0 + t;
  if (n < NN) rp[n] = lo + excl;
  if (b == NB - 1 && t == 0) rp[NN] = ET;
  __syncthreads();
  sdeg[t] = lo + excl;   // reuse as cursor
  __syncthreads();
  for (int i = lo + t; i < hi; i += 512) {
    int2 ed = bedge[i];
    int p = atomicAdd(&sdeg[ed.y - n0], 1);
    esrc[p] = ed.x;
  }
}

// ======================= layer-1 transform (4-node register blocking) =======================
// block 256 = 16 col-threads x 16 node-groups; thread computes 4 nodes x 4 cols.
// W staged in two 32KB halves to keep LDS/block at 32KB (4-5 blocks/CU).
#define FMA4A(a, xv) \
  a.x += xv.x*w0.x + xv.y*w1.x + xv.z*w2.x + xv.w*w3.x; \
  a.y += xv.x*w0.y + xv.y*w1.y + xv.z*w2.y + xv.w*w3.y; \
  a.z += xv.x*w0.z + xv.y*w1.z + xv.z*w2.z + xv.w*w3.z; \
  a.w += xv.x*w0.w + xv.y*w1.w + xv.z*w2.w + xv.w*w3.w;

__global__ __launch_bounds__(256) void k_xform1(
    const float* __restrict__ x,
    const float* __restrict__ Wl, const float* __restrict__ bl,
    const float* __restrict__ Wr, const float* __restrict__ br,
    float* __restrict__ xl1, float* __restrict__ xr1) {
  __shared__ float Wlds[128 * 64];   // 32 KB: half of K at a time
  int tid = threadIdx.x;
  int ci = tid & 15, ni = tid >> 4;
  int cbase = ci * 4;
  int n0 = blockIdx.x * 64 + ni * 4;
  // clamped row pointers (last block may overhang NN)
  int r0 = n0 + 0 < NN ? n0 + 0 : NN - 1;
  int r1 = n0 + 1 < NN ? n0 + 1 : NN - 1;
  int r2 = n0 + 2 < NN ? n0 + 2 : NN - 1;
  int r3 = n0 + 3 < NN ? n0 + 3 : NN - 1;
  const float* xb0 = x + (size_t)r0 * 256;
  const float* xb1 = x + (size_t)r1 * 256;
  const float* xb2 = x + (size_t)r2 * 256;
  const float* xb3 = x + (size_t)r3 * 256;
  float4 acc0 = {0,0,0,0}, acc1 = {0,0,0,0}, acc2 = {0,0,0,0}, acc3 = {0,0,0,0};

  for (int half = 0; half < 2; ++half) {
    int k0 = half * 128;
    __syncthreads();
    for (int i = tid; i < 128 * 64; i += 256) {
      int k = (i >> 6) + k0, c = i & 63;
      Wlds[i] = (c < 32) ? Wl[k * 32 + c] : Wr[k * 32 + (c - 32)];
    }
    __syncthreads();
#pragma unroll 2
    for (int kk = 0; kk < 128; kk += 4) {
      int k = k0 + kk;
      float4 xv0 = *(const float4*)(xb0 + k);
      float4 xv1 = *(const float4*)(xb1 + k);
      float4 xv2 = *(const float4*)(xb2 + k);
      float4 xv3 = *(const float4*)(xb3 + k);
      const float* wr = &Wlds[kk * 64 + cbase];
      float4 w0 = *(const float4*)(wr);
      float4 w1 = *(const float4*)(wr + 64);
      float4 w2 = *(const float4*)(wr + 128);
      float4 w3 = *(const float4*)(wr + 192);
      FMA4A(acc0, xv0)
      FMA4A(acc1, xv1)
      FMA4A(acc2, xv2)
      FMA4A(acc3, xv3)
    }
  }
  // epilogue: bias + store (4 nodes)
  float4 acc[4] = {acc0, acc1, acc2, acc3};
  if (cbase < 32) {
    float4 bv = { bl[cbase], bl[cbase+1], bl[cbase+2], bl[cbase+3] };
#pragma unroll
    for (int j = 0; j < 4; ++j) {
      int n = n0 + j;
      if (n < NN) {
        float4 o = { acc[j].x + bv.x, acc[j].y + bv.y, acc[j].z + bv.z, acc[j].w + bv.w };
        *(float4*)(xl1 + (size_t)n * 32 + cbase) = o;
      }
    }
  } else {
    int c2 = cbase - 32;
    float4 bv = { br[c2], br[c2+1], br[c2+2], br[c2+3] };
#pragma unroll
    for (int j = 0; j < 4; ++j) {
      int n = n0 + j;
      if (n < NN) {
        float4 o = { acc[j].x + bv.x, acc[j].y + bv.y, acc[j].z + bv.z, acc[j].w + bv.w };
        *(float4*)(xr1 + (size_t)n * 32 + c2) = o;
      }
    }
  }
}

// ======================= layer-1 gather, unroll x4 =======================
__global__ __launch_bounds__(256) void k_gather1(
    const int* __restrict__ rp, const int* __restrict__ esrc,
    const float* __restrict__ xl1, const float* __restrict__ xr1,
    const float* __restrict__ att1, const float* __restrict__ bias1,
    float* __restrict__ h) {
  int n = blockIdx.x * 8 + (threadIdx.x >> 5);
  if (n >= NN) return;
  int l = threadIdx.x & 31;
  float av = att1[l];
  float xr = xr1[(size_t)n * 32 + l];
  int rpn = rp[n], dg = rp[n + 1] - rpn;
  float acc = 0.0f, den = 0.0f;
  int j = 0;
  for (; j + 4 <= dg; j += 4) {
    int s0 = esrc[rpn + j + 0];
    int s1 = esrc[rpn + j + 1];
    int s2 = esrc[rpn + j + 2];
    int s3 = esrc[rpn + j + 3];
    float x0 = xl1[(size_t)s0 * 32 + l];
    float x1 = xl1[(size_t)s1 * 32 + l];
    float x2 = xl1[(size_t)s2 * 32 + l];
    float x3 = xl1[(size_t)s3 * 32 + l];
    float p0 = lrelu(x0 + xr) * av;
    float p1 = lrelu(x1 + xr) * av;
    float p2 = lrelu(x2 + xr) * av;
    float p3 = lrelu(x3 + xr) * av;
    p0 += __shfl_xor(p0, 1); p1 += __shfl_xor(p1, 1);
    p2 += __shfl_xor(p2, 1); p3 += __shfl_xor(p3, 1);
    p0 += __shfl_xor(p0, 2); p1 += __shfl_xor(p1, 2);
    p2 += __shfl_xor(p2, 2); p3 += __shfl_xor(p3, 2);
    float w0 = __expf(p0), w1 = __expf(p1), w2 = __expf(p2), w3 = __expf(p3);
    den += w0 + w1 + w2 + w3;
    acc += w0 * x0 + w1 * x1 + w2 * x2 + w3 * x3;
  }
  for (; j < dg; ++j) {
    int s = esrc[rpn + j];
    float xl = xl1[(size_t)s * 32 + l];
    float p = lrelu(xl + xr) * av;
    p += __shfl_xor(p, 1);
    p += __shfl_xor(p, 2);
    float w = __expf(p);
    den += w;
    acc += w * xl;
  }
  float v = acc / (den + 1e-16f) + bias1[l];
  h[(size_t)n * 32 + l] = v > 0.0f ? v : expm1f(v);
}

// ======================= layer-2 transform (4-node register blocking) =======================
// block 256 = 32 col-threads x 8 node-groups; thread computes 4 nodes x 4 cols of 128.
__global__ __launch_bounds__(256) void k_xform2(
    const float* __restrict__ h,
    const float* __restrict__ Wl, const float* __restrict__ bl,
    const float* __restrict__ Wr, const float* __restrict__ br,
    float* __restrict__ hl2, float* __restrict__ hr2) {
  __shared__ float Wlds[32 * 128];   // 16 KB
  int tid = threadIdx.x;
  for (int i = tid; i < 32 * 128; i += 256) {
    int k = i >> 7, c = i & 127;
    Wlds[i] = (c < 64) ? Wl[k * 64 + c] : Wr[k * 64 + (c - 64)];
  }
  __syncthreads();
  int ci = tid & 31, ni = tid >> 5;
  int cbase = ci * 4;
  int n0 = blockIdx.x * 32 + ni * 4;   // grid 3125 * 32 = 100000 exact
  const float* hb0 = h + (size_t)(n0 + 0) * 32;
  const float* hb1 = h + (size_t)(n0 + 1) * 32;
  const float* hb2 = h + (size_t)(n0 + 2) * 32;
  const float* hb3 = h + (size_t)(n0 + 3) * 32;
  float4 acc0 = {0,0,0,0}, acc1 = {0,0,0,0}, acc2 = {0,0,0,0}, acc3 = {0,0,0,0};
#pragma unroll
  for (int k = 0; k < 32; k += 4) {
    float4 xv0 = *(const float4*)(hb0 + k);
    float4 xv1 = *(const float4*)(hb1 + k);
    float4 xv2 = *(const float4*)(hb2 + k);
    float4 xv3 = *(const float4*)(hb3 + k);
    const float* wr = &Wlds[k * 128 + cbase];
    float4 w0 = *(const float4*)(wr);
    float4 w1 = *(const float4*)(wr + 128);
    float4 w2 = *(const float4*)(wr + 256);
    float4 w3 = *(const float4*)(wr + 384);
    FMA4A(acc0, xv0)
    FMA4A(acc1, xv1)
    FMA4A(acc2, xv2)
    FMA4A(acc3, xv3)
  }
  float4 acc[4] = {acc0, acc1, acc2, acc3};
  if (cbase < 64) {
    float4 bv = { bl[cbase], bl[cbase+1], bl[cbase+2], bl[cbase+3] };
#pragma unroll
    for (int j = 0; j < 4; ++j) {
      float4 o = { acc[j].x + bv.x, acc[j].y + bv.y, acc[j].z + bv.z, acc[j].w + bv.w };
      *(float4*)(hl2 + (size_t)(n0 + j) * 64 + cbase) = o;
    }
  } else {
    int c2 = cbase - 64;
    float4 bv = { br[c2], br[c2+1], br[c2+2], br[c2+3] };
#pragma unroll
    for (int j = 0; j < 4; ++j) {
      float4 o = { acc[j].x + bv.x, acc[j].y + bv.y, acc[j].z + bv.z, acc[j].w + bv.w };
      *(float4*)(hr2 + (size_t)(n0 + j) * 64 + c2) = o;
    }
  }
}

// ======================= layer-2 gather (dense out), unroll x2 =======================
__global__ __launch_bounds__(256) void k_gather2(
    const int* __restrict__ rp, const int* __restrict__ esrc,
    const float* __restrict__ hl2, const float* __restrict__ hr2,
    const float* __restrict__ att2, const float* __restrict__ bias2,
    float* __restrict__ out2) {
  int n = (blockIdx.x * 256 + threadIdx.x) >> 3;
  if (n >= NN) return;
  int l8 = threadIdx.x & 7;
  float4 ac0 = *(const float4*)(att2 + l8 * 8);
  float4 ac1 = *(const float4*)(att2 + l8 * 8 + 4);
  float4 bs0 = *(const float4*)(bias2 + l8 * 8);
  float4 bs1 = *(const float4*)(bias2 + l8 * 8 + 4);
  const float4* hrp = (const float4*)(hr2 + (size_t)n * 64 + l8 * 8);
  float4 hr0 = hrp[0], hr1 = hrp[1];
  int rpn = rp[n], dg = rp[n + 1] - rpn;
  float4 a0 = {0,0,0,0}, a1 = {0,0,0,0};
  float den = 0.0f;
  int j = 0;
  for (; j + 2 <= dg; j += 2) {
    int s0 = esrc[rpn + j];
    int s1 = esrc[rpn + j + 1];
    const float4* hp0 = (const float4*)(hl2 + (size_t)s0 * 64 + l8 * 8);
    const float4* hp1 = (const float4*)(hl2 + (size_t)s1 * 64 + l8 * 8);
    float4 u0 = hp0[0], u1 = hp0[1];
    float4 v0 = hp1[0], v1 = hp1[1];
    float p0 = lrelu(u0.x + hr0.x) * ac0.x + lrelu(u0.y + hr0.y) * ac0.y
             + lrelu(u0.z + hr0.z) * ac0.z + lrelu(u0.w + hr0.w) * ac0.w
             + lrelu(u1.x + hr1.x) * ac1.x + lrelu(u1.y + hr1.y) * ac1.y
             + lrelu(u1.z + hr1.z) * ac1.z + lrelu(u1.w + hr1.w) * ac1.w;
    float p1 = lrelu(v0.x + hr0.x) * ac0.x + lrelu(v0.y + hr0.y) * ac0.y
             + lrelu(v0.z + hr0.z) * ac0.z + lrelu(v0.w + hr0.w) * ac0.w
             + lrelu(v1.x + hr1.x) * ac1.x + lrelu(v1.y + hr1.y) * ac1.y
             + lrelu(v1.z + hr1.z) * ac1.z + lrelu(v1.w + hr1.w) * ac1.w;
    p0 += __shfl_xor(p0, 1); p1 += __shfl_xor(p1, 1);
    p0 += __shfl_xor(p0, 2); p1 += __shfl_xor(p1, 2);
    p0 += __shfl_xor(p0, 4); p1 += __shfl_xor(p1, 4);
    float w0 = __expf(p0), w1 = __expf(p1);
    den += w0 + w1;
    a0.x += w0 * u0.x + w1 * v0.x; a0.y += w0 * u0.y + w1 * v0.y;
    a0.z += w0 * u0.z + w1 * v0.z; a0.w += w0 * u0.w + w1 * v0.w;
    a1.x += w0 * u1.x + w1 * v1.x; a1.y += w0 * u1.y + w1 * v1.y;
    a1.z += w0 * u1.z + w1 * v1.z; a1.w += w0 * u1.w + w1 * v1.w;
  }
  for (; j < dg; ++j) {
    int s = esrc[rpn + j];
    const float4* hp = (const float4*)(hl2 + (size_t)s * 64 + l8 * 8);
    float4 u0 = hp[0], u1 = hp[1];
    float p = lrelu(u0.x + hr0.x) * ac0.x + lrelu(u0.y + hr0.y) * ac0.y
            + lrelu(u0.z + hr0.z) * ac0.z + lrelu(u0.w + hr0.w) * ac0.w
            + lrelu(u1.x + hr1.x) * ac1.x + lrelu(u1.y + hr1.y) * ac1.y
            + lrelu(u1.z + hr1.z) * ac1.z + lrelu(u1.w + hr1.w) * ac1.w;
    p += __shfl_xor(p, 1);
    p += __shfl_xor(p, 2);
    p += __shfl_xor(p, 4);
    float w = __expf(p);
    den += w;
    a0.x += w * u0.x; a0.y += w * u0.y; a0.z += w * u0.z; a0.w += w * u0.w;
    a1.x += w * u1.x; a1.y += w * u1.y; a1.z += w * u1.z; a1.w += w * u1.w;
  }
  float inv = 1.0f / (den + 1e-16f);
  float4 o0 = { a0.x * inv + bs0.x, a0.y * inv + bs0.y, a0.z * inv + bs0.z, a0.w * inv + bs0.w };
  float4 o1 = { a1.x * inv + bs1.x, a1.y * inv + bs1.y, a1.z * inv + bs1.z, a1.w * inv + bs1.w };
  float4* op = (float4*)(out2 + (size_t)n * 64 + l8 * 8);
  op[0] = o0; op[1] = o1;
}

// ======================= pooling =======================
__global__ __launch_bounds__(256) void k_pool(
    const float* __restrict__ out2, const int* __restrict__ batch,
    float* __restrict__ ppart) {
  __shared__ float ssum[NG * 64];
  __shared__ float scnt[NG];
  int tid = threadIdx.x;
  for (int i = tid; i < NG * 64; i += 256) ssum[i] = 0.0f;
  if (tid < NG) scnt[tid] = 0.0f;
  __syncthreads();
  int total = NN * 64;
  for (int idx = blockIdx.x * 256 + tid; idx < total; idx += gridDim.x * 256) {
    int n = idx >> 6, c = idx & 63;
    int g = batch[n];
    atomicAdd(&ssum[g * 64 + c], out2[idx]);
    if (c == 0) atomicAdd(&scnt[g], 1.0f);
  }
  __syncthreads();
  float* pb = ppart + (size_t)blockIdx.x * (NG * 64 + NG);
  for (int i = tid; i < NG * 64; i += 256) pb[i] = ssum[i];
  if (tid < NG) pb[NG * 64 + tid] = scnt[tid];
}

__global__ __launch_bounds__(256) void k_final(
    const float* __restrict__ ppart, float* __restrict__ out) {
  int i = blockIdx.x * 256 + threadIdx.x;
  if (i >= NG * 64) return;
  int g = i >> 6;
  float s = 0.0f, c = 0.0f;
  for (int b = 0; b < NPB; ++b) {
    const float* pb = ppart + (size_t)b * (NG * 64 + NG);
    s += pb[i];
    c += pb[NG * 64 + g];
  }
  out[i] = s / fmaxf(c, 1.0f);
}

extern "C" void kernel_launch(void* const* d_in, const int* in_sizes, int n_in,
                              void* d_out, int out_size, void* d_ws, size_t ws_size,
                              hipStream_t stream) {
  const float* x     = (const float*)d_in[0];
  const int*   ei    = (const int*)d_in[1];
  const int*   batch = (const int*)d_in[2];
  const float* W1l   = (const float*)d_in[3];
  const float* b1l   = (const float*)d_in[4];
  const float* W1r   = (const float*)d_in[5];
  const float* b1r   = (const float*)d_in[6];
  const float* att1  = (const float*)d_in[7];
  const float* bias1 = (const float*)d_in[8];
  const float* W2l   = (const float*)d_in[9];
  const float* b2l   = (const float*)d_in[10];
  const float* W2r   = (const float*)d_in[11];
  const float* b2r   = (const float*)d_in[12];
  const float* att2  = (const float*)d_in[13];
  const float* bias2 = (const float*)d_in[14];
  float* ws = (float*)d_ws;
  int*   wi = (int*)d_ws;
  float* out = (float*)d_out;

  hipMemsetAsync(wi + OFF_BCNT, 0, NB * 4, stream);

  // CSR build via bucket counting sort (LDS-reorder partition)
  k_bcount<<<512, 256, 0, stream>>>(ei, wi + OFF_BCNT);
  k_bscan<<<1, 256, 0, stream>>>(wi + OFF_BCNT, wi + OFF_BOFF, wi + OFF_GCUR);
  k_part<<<PBLOCKS, 512, 0, stream>>>(ei, wi + OFF_GCUR, (int2*)(wi + OFF_BEDGE));
  k_csr<<<NB, 512, 0, stream>>>(wi + OFF_BOFF, (const int2*)(wi + OFF_BEDGE),
                                wi + OFF_RP, wi + OFF_ESRC);

  // layer 1
  k_xform1<<<(NN + 63) / 64, 256, 0, stream>>>(x, W1l, b1l, W1r, b1r,
                                               ws + OFF_XL1, ws + OFF_XR1);
  k_gather1<<<NN / 8, 256, 0, stream>>>(wi + OFF_RP, wi + OFF_ESRC,
                                        ws + OFF_XL1, ws + OFF_XR1, att1, bias1, ws + OFF_H);
  // layer 2 (xform2 overwrites bedge region — bedge is dead by then)
  k_xform2<<<NN / 32, 256, 0, stream>>>(ws + OFF_H, W2l, b2l, W2r, b2r,
                                        ws + OFF_HL2, ws + OFF_HR2);
  k_gather2<<<(NN * 8 + 255) / 256, 256, 0, stream>>>(wi + OFF_RP, wi + OFF_ESRC,
                                                      ws + OFF_HL2, ws + OFF_HR2, att2, bias2,
                                                      ws + OFF_OUT2);
  k_pool<<<NPB, 256, 0, stream>>>(ws + OFF_OUT2, batch, ws + OFF_PPART);
  k_final<<<16, 256, 0, stream>>>(ws + OFF_PPART, out);
}

// Round 8
// 418.609 us; speedup vs baseline: 1.8905x; 1.1568x over previous
//
#include <hip/hip_runtime.h>
#include <math.h>

#define NN 100000
#define EE 3200000
#define ET (EE + NN)
#define NG 64
#define NPB 128        // pool partial blocks

// bucket sort params
#define NB 196         // ceil(NN/512) buckets
#define BWID 512       // nodes per bucket (dst >> 9)
#define PCHUNK 8192    // edges per partition block
#define PBLOCKS ((ET + PCHUNK - 1) / PCHUNK)

// workspace layout (4-byte units)
#define OFF_XL1B  0u           /* ushort[NN*32] = 1.6M floats */
#define OFF_XR1   1600000u     /* f32 3.2M */
#define OFF_H     4800000u     /* f32 3.2M */
#define OFF_HL2B  8000000u     /* ushort[NN*64] = 3.2M floats */
#define OFF_HR2   11200000u    /* f32 6.4M  (ends 17.6M) */
#define OFF_OUT2  0u           /* f32 6.4M, reuses XL1B/XR1/H-head (dead at gather2) */
#define OFF_BEDGE 8000000u     /* int2[ET]=6.6M ints, aliases HL2B+HR2 head (dead until xform2) */
#define OFF_PPART 17600000u    /* NPB*4160 = 532480 */
#define OFF_RP    18132480u    /* 100096 */
#define OFF_ESRC  18232576u    /* ET */
#define OFF_BCNT  21532576u
#define OFF_BOFF  21532832u
#define OFF_GCUR  21533088u
#define WS_UNITS  21533344u

__device__ __forceinline__ float lrelu(float v) { return v > 0.0f ? v : 0.2f * v; }

__device__ __forceinline__ unsigned pack_bf2(float a, float b) {
  unsigned ua = __float_as_uint(a), ub = __float_as_uint(b);
  ua = (ua + 0x7FFFu + ((ua >> 16) & 1u)) >> 16;
  ub = (ub + 0x7FFFu + ((ub >> 16) & 1u)) & 0xFFFF0000u;
  return ua | ub;
}
__device__ __forceinline__ float bf_lo(unsigned u) { return __uint_as_float(u << 16); }
__device__ __forceinline__ float bf_hi(unsigned u) { return __uint_as_float(u & 0xFFFF0000u); }

// ======================= bucket counting sort: CSR build =======================
__global__ __launch_bounds__(256) void k_bcount(const int* __restrict__ ei,
                                                int* __restrict__ bcnt) {
  __shared__ int h[NB];
  for (int i = threadIdx.x; i < NB; i += 256) h[i] = 0;
  __syncthreads();
  for (long e = (long)blockIdx.x * 256 + threadIdx.x; e < ET; e += (long)gridDim.x * 256) {
    int d = (e < EE) ? ei[EE + e] : (int)(e - EE);
    atomicAdd(&h[d >> 9], 1);
  }
  __syncthreads();
  for (int i = threadIdx.x; i < NB; i += 256) if (h[i]) atomicAdd(&bcnt[i], h[i]);
}

__global__ __launch_bounds__(256) void k_bscan(const int* __restrict__ bcnt,
                                               int* __restrict__ boff, int* __restrict__ gcur) {
  __shared__ int sd[256];
  int t = threadIdx.x;
  int v = (t < NB) ? bcnt[t] : 0;
  sd[t] = v;
  __syncthreads();
  for (int o = 1; o < 256; o <<= 1) {
    int u = (t >= o) ? sd[t - o] : 0;
    __syncthreads();
    sd[t] += u;
    __syncthreads();
  }
  if (t < NB) { boff[t] = sd[t] - v; gcur[t] = sd[t] - v; }
  if (t == 0) boff[NB] = ET;
}

// LDS-reorder partition: 8192 edges/block -> bucket-grouped in LDS -> dense writes
__global__ __launch_bounds__(512) void k_part(const int* __restrict__ ei,
                                              int* __restrict__ gcur,
                                              int2* __restrict__ bedge) {
  __shared__ int  cnt[NB];
  __shared__ int  lbase[NB];
  __shared__ int  gbase[NB];
  __shared__ int  sc[256];
  __shared__ int2 buf[PCHUNK];
  int tid = threadIdx.x;
  long e0 = (long)blockIdx.x * PCHUNK;
  int nedge = (e0 + PCHUNK <= ET) ? PCHUNK : (int)(ET - e0);

  for (int i = tid; i < NB; i += 512) cnt[i] = 0;
  __syncthreads();
  for (int i = tid; i < nedge; i += 512) {
    long e = e0 + i;
    int d = (e < EE) ? ei[EE + e] : (int)(e - EE);
    atomicAdd(&cnt[d >> 9], 1);
  }
  __syncthreads();
  if (tid < 256) sc[tid] = (tid < NB) ? cnt[tid] : 0;
  __syncthreads();
  for (int o = 1; o < 256; o <<= 1) {
    int u = (tid < 256 && tid >= o) ? sc[tid - o] : 0;
    __syncthreads();
    if (tid < 256) sc[tid] += u;
    __syncthreads();
  }
  if (tid < NB) lbase[tid] = sc[tid] - cnt[tid];
  __syncthreads();
  if (tid < NB) {
    int c = cnt[tid];
    gbase[tid] = c ? atomicAdd(&gcur[tid], c) : 0;
    cnt[tid] = 0;
  }
  __syncthreads();
  for (int i = tid; i < nedge; i += 512) {
    long e = e0 + i;
    int s, d;
    if (e < EE) { s = ei[e]; d = ei[EE + e]; }
    else { s = (int)(e - EE); d = s; }
    int b = d >> 9;
    int r = atomicAdd(&cnt[b], 1);
    buf[lbase[b] + r] = make_int2(s, d);
  }
  __syncthreads();
  for (int i = tid; i < nedge; i += 512) {
    int2 ed = buf[i];
    int b = ed.y >> 9;
    bedge[gbase[b] + (i - lbase[b])] = ed;
  }
}

// per-bucket: LDS node-degree count + scan -> rp; LDS cursors -> esrc
__global__ __launch_bounds__(512) void k_csr(const int* __restrict__ boff,
                                             const int2* __restrict__ bedge,
                                             int* __restrict__ rp, int* __restrict__ esrc) {
  __shared__ int sdeg[BWID];
  __shared__ int sscan[BWID];
  int b = blockIdx.x, t = threadIdx.x;
  int n0 = b * BWID;
  int lo = boff[b], hi = boff[b + 1];
  sdeg[t] = 0;
  __syncthreads();
  for (int i = lo + t; i < hi; i += 512) {
    int2 ed = bedge[i];
    atomicAdd(&sdeg[ed.y - n0], 1);
  }
  __syncthreads();
  int v = sdeg[t];
  sscan[t] = v;
  __syncthreads();
  for (int o = 1; o < 512; o <<= 1) {
    int u = (t >= o) ? sscan[t - o] : 0;
    __syncthreads();
    sscan[t] += u;
    __syncthreads();
  }
  int excl = sscan[t] - v;
  int n = n0 + t;
  if (n < NN) rp[n] = lo + excl;
  if (b == NB - 1 && t == 0) rp[NN] = ET;
  __syncthreads();
  sdeg[t] = lo + excl;   // reuse as cursor
  __syncthreads();
  for (int i = lo + t; i < hi; i += 512) {
    int2 ed = bedge[i];
    int p = atomicAdd(&sdeg[ed.y - n0], 1);
    esrc[p] = ed.x;
  }
}

// ======================= layer-1 transform (4-node register blocking) =======================
#define FMA4A(a, xv) \
  a.x += xv.x*w0.x + xv.y*w1.x + xv.z*w2.x + xv.w*w3.x; \
  a.y += xv.x*w0.y + xv.y*w1.y + xv.z*w2.y + xv.w*w3.y; \
  a.z += xv.x*w0.z + xv.y*w1.z + xv.z*w2.z + xv.w*w3.z; \
  a.w += xv.x*w0.w + xv.y*w1.w + xv.z*w2.w + xv.w*w3.w;

__global__ __launch_bounds__(256) void k_xform1(
    const float* __restrict__ x,
    const float* __restrict__ Wl, const float* __restrict__ bl,
    const float* __restrict__ Wr, const float* __restrict__ br,
    unsigned short* __restrict__ xl1b, float* __restrict__ xr1) {
  __shared__ float Wlds[128 * 64];   // 32 KB: half of K at a time
  int tid = threadIdx.x;
  int ci = tid & 15, ni = tid >> 4;
  int cbase = ci * 4;
  int n0 = blockIdx.x * 64 + ni * 4;
  int r0 = n0 + 0 < NN ? n0 + 0 : NN - 1;
  int r1 = n0 + 1 < NN ? n0 + 1 : NN - 1;
  int r2 = n0 + 2 < NN ? n0 + 2 : NN - 1;
  int r3 = n0 + 3 < NN ? n0 + 3 : NN - 1;
  const float* xb0 = x + (size_t)r0 * 256;
  const float* xb1 = x + (size_t)r1 * 256;
  const float* xb2 = x + (size_t)r2 * 256;
  const float* xb3 = x + (size_t)r3 * 256;
  float4 acc0 = {0,0,0,0}, acc1 = {0,0,0,0}, acc2 = {0,0,0,0}, acc3 = {0,0,0,0};

  for (int half = 0; half < 2; ++half) {
    int k0 = half * 128;
    __syncthreads();
    for (int i = tid; i < 128 * 64; i += 256) {
      int k = (i >> 6) + k0, c = i & 63;
      Wlds[i] = (c < 32) ? Wl[k * 32 + c] : Wr[k * 32 + (c - 32)];
    }
    __syncthreads();
#pragma unroll 2
    for (int kk = 0; kk < 128; kk += 4) {
      int k = k0 + kk;
      float4 xv0 = *(const float4*)(xb0 + k);
      float4 xv1 = *(const float4*)(xb1 + k);
      float4 xv2 = *(const float4*)(xb2 + k);
      float4 xv3 = *(const float4*)(xb3 + k);
      const float* wr = &Wlds[kk * 64 + cbase];
      float4 w0 = *(const float4*)(wr);
      float4 w1 = *(const float4*)(wr + 64);
      float4 w2 = *(const float4*)(wr + 128);
      float4 w3 = *(const float4*)(wr + 192);
      FMA4A(acc0, xv0)
      FMA4A(acc1, xv1)
      FMA4A(acc2, xv2)
      FMA4A(acc3, xv3)
    }
  }
  float4 acc[4] = {acc0, acc1, acc2, acc3};
  if (cbase < 32) {
    float4 bv = { bl[cbase], bl[cbase+1], bl[cbase+2], bl[cbase+3] };
#pragma unroll
    for (int j = 0; j < 4; ++j) {
      int n = n0 + j;
      if (n < NN) {
        uint2 o = { pack_bf2(acc[j].x + bv.x, acc[j].y + bv.y),
                    pack_bf2(acc[j].z + bv.z, acc[j].w + bv.w) };
        *(uint2*)(xl1b + (size_t)n * 32 + cbase) = o;
      }
    }
  } else {
    int c2 = cbase - 32;
    float4 bv = { br[c2], br[c2+1], br[c2+2], br[c2+3] };
#pragma unroll
    for (int j = 0; j < 4; ++j) {
      int n = n0 + j;
      if (n < NN) {
        float4 o = { acc[j].x + bv.x, acc[j].y + bv.y, acc[j].z + bv.z, acc[j].w + bv.w };
        *(float4*)(xr1 + (size_t)n * 32 + c2) = o;
      }
    }
  }
}

// ======================= layer-1 gather (bf16 xl), unroll x4 =======================
__global__ __launch_bounds__(256) void k_gather1(
    const int* __restrict__ rp, const int* __restrict__ esrc,
    const unsigned short* __restrict__ xl1b, const float* __restrict__ xr1,
    const float* __restrict__ att1, const float* __restrict__ bias1,
    float* __restrict__ h) {
  int n = blockIdx.x * 8 + (threadIdx.x >> 5);
  if (n >= NN) return;
  int l = threadIdx.x & 31;
  float av = att1[l];
  float xr = xr1[(size_t)n * 32 + l];
  int rpn = rp[n], dg = rp[n + 1] - rpn;
  float acc = 0.0f, den = 0.0f;
  int j = 0;
  for (; j + 4 <= dg; j += 4) {
    int s0 = esrc[rpn + j + 0];
    int s1 = esrc[rpn + j + 1];
    int s2 = esrc[rpn + j + 2];
    int s3 = esrc[rpn + j + 3];
    float x0 = bf_lo(xl1b[(size_t)s0 * 32 + l]);
    float x1 = bf_lo(xl1b[(size_t)s1 * 32 + l]);
    float x2 = bf_lo(xl1b[(size_t)s2 * 32 + l]);
    float x3 = bf_lo(xl1b[(size_t)s3 * 32 + l]);
    float p0 = lrelu(x0 + xr) * av;
    float p1 = lrelu(x1 + xr) * av;
    float p2 = lrelu(x2 + xr) * av;
    float p3 = lrelu(x3 + xr) * av;
    p0 += __shfl_xor(p0, 1); p1 += __shfl_xor(p1, 1);
    p2 += __shfl_xor(p2, 1); p3 += __shfl_xor(p3, 1);
    p0 += __shfl_xor(p0, 2); p1 += __shfl_xor(p1, 2);
    p2 += __shfl_xor(p2, 2); p3 += __shfl_xor(p3, 2);
    float w0 = __expf(p0), w1 = __expf(p1), w2 = __expf(p2), w3 = __expf(p3);
    den += w0 + w1 + w2 + w3;
    acc += w0 * x0 + w1 * x1 + w2 * x2 + w3 * x3;
  }
  for (; j < dg; ++j) {
    int s = esrc[rpn + j];
    float xl = bf_lo(xl1b[(size_t)s * 32 + l]);
    float p = lrelu(xl + xr) * av;
    p += __shfl_xor(p, 1);
    p += __shfl_xor(p, 2);
    float w = __expf(p);
    den += w;
    acc += w * xl;
  }
  float v = acc / (den + 1e-16f) + bias1[l];
  h[(size_t)n * 32 + l] = v > 0.0f ? v : expm1f(v);
}

// ======================= layer-2 transform (4-node register blocking) =======================
__global__ __launch_bounds__(256) void k_xform2(
    const float* __restrict__ h,
    const float* __restrict__ Wl, const float* __restrict__ bl,
    const float* __restrict__ Wr, const float* __restrict__ br,
    unsigned short* __restrict__ hl2b, float* __restrict__ hr2) {
  __shared__ float Wlds[32 * 128];   // 16 KB
  int tid = threadIdx.x;
  for (int i = tid; i < 32 * 128; i += 256) {
    int k = i >> 7, c = i & 127;
    Wlds[i] = (c < 64) ? Wl[k * 64 + c] : Wr[k * 64 + (c - 64)];
  }
  __syncthreads();
  int ci = tid & 31, ni = tid >> 5;
  int cbase = ci * 4;
  int n0 = blockIdx.x * 32 + ni * 4;   // grid 3125 * 32 = 100000 exact
  const float* hb0 = h + (size_t)(n0 + 0) * 32;
  const float* hb1 = h + (size_t)(n0 + 1) * 32;
  const float* hb2 = h + (size_t)(n0 + 2) * 32;
  const float* hb3 = h + (size_t)(n0 + 3) * 32;
  float4 acc0 = {0,0,0,0}, acc1 = {0,0,0,0}, acc2 = {0,0,0,0}, acc3 = {0,0,0,0};
#pragma unroll
  for (int k = 0; k < 32; k += 4) {
    float4 xv0 = *(const float4*)(hb0 + k);
    float4 xv1 = *(const float4*)(hb1 + k);
    float4 xv2 = *(const float4*)(hb2 + k);
    float4 xv3 = *(const float4*)(hb3 + k);
    const float* wr = &Wlds[k * 128 + cbase];
    float4 w0 = *(const float4*)(wr);
    float4 w1 = *(const float4*)(wr + 128);
    float4 w2 = *(const float4*)(wr + 256);
    float4 w3 = *(const float4*)(wr + 384);
    FMA4A(acc0, xv0)
    FMA4A(acc1, xv1)
    FMA4A(acc2, xv2)
    FMA4A(acc3, xv3)
  }
  float4 acc[4] = {acc0, acc1, acc2, acc3};
  if (cbase < 64) {
    float4 bv = { bl[cbase], bl[cbase+1], bl[cbase+2], bl[cbase+3] };
#pragma unroll
    for (int j = 0; j < 4; ++j) {
      uint2 o = { pack_bf2(acc[j].x + bv.x, acc[j].y + bv.y),
                  pack_bf2(acc[j].z + bv.z, acc[j].w + bv.w) };
      *(uint2*)(hl2b + (size_t)(n0 + j) * 64 + cbase) = o;
    }
  } else {
    int c2 = cbase - 64;
    float4 bv = { br[c2], br[c2+1], br[c2+2], br[c2+3] };
#pragma unroll
    for (int j = 0; j < 4; ++j) {
      float4 o = { acc[j].x + bv.x, acc[j].y + bv.y, acc[j].z + bv.z, acc[j].w + bv.w };
      *(float4*)(hr2 + (size_t)(n0 + j) * 64 + c2) = o;
    }
  }
}

// ======================= layer-2 gather (bf16 hl), unroll x2 =======================
__global__ __launch_bounds__(256) void k_gather2(
    const int* __restrict__ rp, const int* __restrict__ esrc,
    const unsigned short* __restrict__ hl2b, const float* __restrict__ hr2,
    const float* __restrict__ att2, const float* __restrict__ bias2,
    float* __restrict__ out2) {
  int n = (blockIdx.x * 256 + threadIdx.x) >> 3;
  if (n >= NN) return;
  int l8 = threadIdx.x & 7;
  float4 ac0 = *(const float4*)(att2 + l8 * 8);
  float4 ac1 = *(const float4*)(att2 + l8 * 8 + 4);
  float4 bs0 = *(const float4*)(bias2 + l8 * 8);
  float4 bs1 = *(const float4*)(bias2 + l8 * 8 + 4);
  const float4* hrp = (const float4*)(hr2 + (size_t)n * 64 + l8 * 8);
  float4 hr0 = hrp[0], hr1 = hrp[1];
  int rpn = rp[n], dg = rp[n + 1] - rpn;
  float4 a0 = {0,0,0,0}, a1 = {0,0,0,0};
  float den = 0.0f;
  int j = 0;
  for (; j + 2 <= dg; j += 2) {
    int s0 = esrc[rpn + j];
    int s1 = esrc[rpn + j + 1];
    uint4 q0 = *(const uint4*)(hl2b + (size_t)s0 * 64 + l8 * 8);
    uint4 q1 = *(const uint4*)(hl2b + (size_t)s1 * 64 + l8 * 8);
    float4 u0 = { bf_lo(q0.x), bf_hi(q0.x), bf_lo(q0.y), bf_hi(q0.y) };
    float4 u1 = { bf_lo(q0.z), bf_hi(q0.z), bf_lo(q0.w), bf_hi(q0.w) };
    float4 v0 = { bf_lo(q1.x), bf_hi(q1.x), bf_lo(q1.y), bf_hi(q1.y) };
    float4 v1 = { bf_lo(q1.z), bf_hi(q1.z), bf_lo(q1.w), bf_hi(q1.w) };
    float p0 = lrelu(u0.x + hr0.x) * ac0.x + lrelu(u0.y + hr0.y) * ac0.y
             + lrelu(u0.z + hr0.z) * ac0.z + lrelu(u0.w + hr0.w) * ac0.w
             + lrelu(u1.x + hr1.x) * ac1.x + lrelu(u1.y + hr1.y) * ac1.y
             + lrelu(u1.z + hr1.z) * ac1.z + lrelu(u1.w + hr1.w) * ac1.w;
    float p1 = lrelu(v0.x + hr0.x) * ac0.x + lrelu(v0.y + hr0.y) * ac0.y
             + lrelu(v0.z + hr0.z) * ac0.z + lrelu(v0.w + hr0.w) * ac0.w
             + lrelu(v1.x + hr1.x) * ac1.x + lrelu(v1.y + hr1.y) * ac1.y
             + lrelu(v1.z + hr1.z) * ac1.z + lrelu(v1.w + hr1.w) * ac1.w;
    p0 += __shfl_xor(p0, 1); p1 += __shfl_xor(p1, 1);
    p0 += __shfl_xor(p0, 2); p1 += __shfl_xor(p1, 2);
    p0 += __shfl_xor(p0, 4); p1 += __shfl_xor(p1, 4);
    float w0 = __expf(p0), w1 = __expf(p1);
    den += w0 + w1;
    a0.x += w0 * u0.x + w1 * v0.x; a0.y += w0 * u0.y + w1 * v0.y;
    a0.z += w0 * u0.z + w1 * v0.z; a0.w += w0 * u0.w + w1 * v0.w;
    a1.x += w0 * u1.x + w1 * v1.x; a1.y += w0 * u1.y + w1 * v1.y;
    a1.z += w0 * u1.z + w1 * v1.z; a1.w += w0 * u1.w + w1 * v1.w;
  }
  for (; j < dg; ++j) {
    int s = esrc[rpn + j];
    uint4 q0 = *(const uint4*)(hl2b + (size_t)s * 64 + l8 * 8);
    float4 u0 = { bf_lo(q0.x), bf_hi(q0.x), bf_lo(q0.y), bf_hi(q0.y) };
    float4 u1 = { bf_lo(q0.z), bf_hi(q0.z), bf_lo(q0.w), bf_hi(q0.w) };
    float p = lrelu(u0.x + hr0.x) * ac0.x + lrelu(u0.y + hr0.y) * ac0.y
            + lrelu(u0.z + hr0.z) * ac0.z + lrelu(u0.w + hr0.w) * ac0.w
            + lrelu(u1.x + hr1.x) * ac1.x + lrelu(u1.y + hr1.y) * ac1.y
            + lrelu(u1.z + hr1.z) * ac1.z + lrelu(u1.w + hr1.w) * ac1.w;
    p += __shfl_xor(p, 1);
    p += __shfl_xor(p, 2);
    p += __shfl_xor(p, 4);
    float w = __expf(p);
    den += w;
    a0.x += w * u0.x; a0.y += w * u0.y; a0.z += w * u0.z; a0.w += w * u0.w;
    a1.x += w * u1.x; a1.y += w * u1.y; a1.z += w * u1.z; a1.w += w * u1.w;
  }
  float inv = 1.0f / (den + 1e-16f);
  float4 o0 = { a0.x * inv + bs0.x, a0.y * inv + bs0.y, a0.z * inv + bs0.z, a0.w * inv + bs0.w };
  float4 o1 = { a1.x * inv + bs1.x, a1.y * inv + bs1.y, a1.z * inv + bs1.z, a1.w * inv + bs1.w };
  float4* op = (float4*)(out2 + (size_t)n * 64 + l8 * 8);
  op[0] = o0; op[1] = o1;
}

// ======================= pooling =======================
__global__ __launch_bounds__(256) void k_pool(
    const float* __restrict__ out2, const int* __restrict__ batch,
    float* __restrict__ ppart) {
  __shared__ float ssum[NG * 64];
  __shared__ float scnt[NG];
  int tid = threadIdx.x;
  for (int i = tid; i < NG * 64; i += 256) ssum[i] = 0.0f;
  if (tid < NG) scnt[tid] = 0.0f;
  __syncthreads();
  int total = NN * 64;
  for (int idx = blockIdx.x * 256 + tid; idx < total; idx += gridDim.x * 256) {
    int n = idx >> 6, c = idx & 63;
    int g = batch[n];
    atomicAdd(&ssum[g * 64 + c], out2[idx]);
    if (c == 0) atomicAdd(&scnt[g], 1.0f);
  }
  __syncthreads();
  float* pb = ppart + (size_t)blockIdx.x * (NG * 64 + NG);
  for (int i = tid; i < NG * 64; i += 256) pb[i] = ssum[i];
  if (tid < NG) pb[NG * 64 + tid] = scnt[tid];
}

__global__ __launch_bounds__(256) void k_final(
    const float* __restrict__ ppart, float* __restrict__ out) {
  int i = blockIdx.x * 256 + threadIdx.x;
  if (i >= NG * 64) return;
  int g = i >> 6;
  float s = 0.0f, c = 0.0f;
  for (int b = 0; b < NPB; ++b) {
    const float* pb = ppart + (size_t)b * (NG * 64 + NG);
    s += pb[i];
    c += pb[NG * 64 + g];
  }
  out[i] = s / fmaxf(c, 1.0f);
}

extern "C" void kernel_launch(void* const* d_in, const int* in_sizes, int n_in,
                              void* d_out, int out_size, void* d_ws, size_t ws_size,
                              hipStream_t stream) {
  const float* x     = (const float*)d_in[0];
  const int*   ei    = (const int*)d_in[1];
  const int*   batch = (const int*)d_in[2];
  const float* W1l   = (const float*)d_in[3];
  const float* b1l   = (const float*)d_in[4];
  const float* W1r   = (const float*)d_in[5];
  const float* b1r   = (const float*)d_in[6];
  const float* att1  = (const float*)d_in[7];
  const float* bias1 = (const float*)d_in[8];
  const float* W2l   = (const float*)d_in[9];
  const float* b2l   = (const float*)d_in[10];
  const float* W2r   = (const float*)d_in[11];
  const float* b2r   = (const float*)d_in[12];
  const float* att2  = (const float*)d_in[13];
  const float* bias2 = (const float*)d_in[14];
  float* ws = (float*)d_ws;
  int*   wi = (int*)d_ws;
  float* out = (float*)d_out;

  hipMemsetAsync(wi + OFF_BCNT, 0, NB * 4, stream);

  // CSR build via bucket counting sort (LDS-reorder partition)
  k_bcount<<<512, 256, 0, stream>>>(ei, wi + OFF_BCNT);
  k_bscan<<<1, 256, 0, stream>>>(wi + OFF_BCNT, wi + OFF_BOFF, wi + OFF_GCUR);
  k_part<<<PBLOCKS, 512, 0, stream>>>(ei, wi + OFF_GCUR, (int2*)(wi + OFF_BEDGE));
  k_csr<<<NB, 512, 0, stream>>>(wi + OFF_BOFF, (const int2*)(wi + OFF_BEDGE),
                                wi + OFF_RP, wi + OFF_ESRC);

  // layer 1
  k_xform1<<<(NN + 63) / 64, 256, 0, stream>>>(x, W1l, b1l, W1r, b1r,
                                               (unsigned short*)(ws + OFF_XL1B), ws + OFF_XR1);
  k_gather1<<<NN / 8, 256, 0, stream>>>(wi + OFF_RP, wi + OFF_ESRC,
                                        (const unsigned short*)(ws + OFF_XL1B), ws + OFF_XR1,
                                        att1, bias1, ws + OFF_H);
  // layer 2 (xform2 overwrites bedge region — bedge is dead by then)
  k_xform2<<<NN / 32, 256, 0, stream>>>(ws + OFF_H, W2l, b2l, W2r, b2r,
                                        (unsigned short*)(ws + OFF_HL2B), ws + OFF_HR2);
  k_gather2<<<(NN * 8 + 255) / 256, 256, 0, stream>>>(wi + OFF_RP, wi + OFF_ESRC,
                                                      (const unsigned short*)(ws + OFF_HL2B),
                                                      ws + OFF_HR2, att2, bias2,
                                                      ws + OFF_OUT2);
  k_pool<<<NPB, 256, 0, stream>>>(ws + OFF_OUT2, batch, ws + OFF_PPART);
  k_final<<<16, 256, 0, stream>>>(ws + OFF_PPART, out);
}

// Round 9
// 400.428 us; speedup vs baseline: 1.9763x; 1.0454x over previous
//
#include <hip/hip_runtime.h>
#include <math.h>

#define NN 100000
#define EE 3200000
#define ET (EE + NN)
#define NG 64

// bucket sort params
#define NB 196         // ceil(NN/512) buckets
#define BWID 512       // nodes per bucket (dst >> 9)
#define PCHUNK 8192    // edges per partition block
#define PBLOCKS ((ET + PCHUNK - 1) / PCHUNK)

// workspace layout (4-byte units)
#define OFF_XL1B  0u           /* ushort[NN*32] = 1.6M floats */
#define OFF_XR1   1600000u     /* f32 3.2M -> ends 4.8M */
#define OFF_H     4800000u     /* f32 3.2M -> 8.0M */
#define OFF_HL2B  8000000u     /* ushort[NN*64] = 3.2M floats -> 11.2M */
#define OFF_HR2   11200000u    /* f32 6.4M -> 17.6M */
#define OFF_BEDGE 8000000u     /* int2[ET] = 6.6M floats, aliases HL2B/HR2 head (dead before xform2) */
#define OFF_RP    17600000u    /* 100096 */
#define OFF_ESRC  17700096u    /* ET = 3.3M -> 21000096 */
#define OFF_POOL  21000096u    /* 4096 */
#define OFF_CNTG  21004192u    /* 64 */
#define OFF_BCNT  21004256u    /* 256 */
#define OFF_BOFF  21004512u    /* 256 */
#define OFF_GCUR  21004768u    /* 256 */
#define WS_UNITS  21005024u

__device__ __forceinline__ float lrelu(float v) { return v > 0.0f ? v : 0.2f * v; }

__device__ __forceinline__ unsigned pack_bf2(float a, float b) {
  unsigned ua = __float_as_uint(a), ub = __float_as_uint(b);
  ua = (ua + 0x7FFFu + ((ua >> 16) & 1u)) >> 16;
  ub = (ub + 0x7FFFu + ((ub >> 16) & 1u)) & 0xFFFF0000u;
  return ua | ub;
}
__device__ __forceinline__ float bf_lo(unsigned u) { return __uint_as_float(u << 16); }
__device__ __forceinline__ float bf_hi(unsigned u) { return __uint_as_float(u & 0xFFFF0000u); }

// ======================= bucket counting sort: CSR build =======================
__global__ __launch_bounds__(256) void k_bcount(const int* __restrict__ ei,
                                                int* __restrict__ bcnt) {
  __shared__ int h[NB];
  for (int i = threadIdx.x; i < NB; i += 256) h[i] = 0;
  __syncthreads();
  for (long e = (long)blockIdx.x * 256 + threadIdx.x; e < ET; e += (long)gridDim.x * 256) {
    int d = (e < EE) ? ei[EE + e] : (int)(e - EE);
    atomicAdd(&h[d >> 9], 1);
  }
  __syncthreads();
  for (int i = threadIdx.x; i < NB; i += 256) if (h[i]) atomicAdd(&bcnt[i], h[i]);
}

__global__ __launch_bounds__(256) void k_bscan(const int* __restrict__ bcnt,
                                               int* __restrict__ boff, int* __restrict__ gcur) {
  __shared__ int sd[256];
  int t = threadIdx.x;
  int v = (t < NB) ? bcnt[t] : 0;
  sd[t] = v;
  __syncthreads();
  for (int o = 1; o < 256; o <<= 1) {
    int u = (t >= o) ? sd[t - o] : 0;
    __syncthreads();
    sd[t] += u;
    __syncthreads();
  }
  if (t < NB) { boff[t] = sd[t] - v; gcur[t] = sd[t] - v; }
  if (t == 0) boff[NB] = ET;
}

// LDS-reorder partition: 8192 edges/block -> bucket-grouped in LDS -> dense writes
__global__ __launch_bounds__(512) void k_part(const int* __restrict__ ei,
                                              int* __restrict__ gcur,
                                              int2* __restrict__ bedge) {
  __shared__ int  cnt[NB];
  __shared__ int  lbase[NB];
  __shared__ int  gbase[NB];
  __shared__ int  sc[256];
  __shared__ int2 buf[PCHUNK];
  int tid = threadIdx.x;
  long e0 = (long)blockIdx.x * PCHUNK;
  int nedge = (e0 + PCHUNK <= ET) ? PCHUNK : (int)(ET - e0);

  for (int i = tid; i < NB; i += 512) cnt[i] = 0;
  __syncthreads();
  for (int i = tid; i < nedge; i += 512) {
    long e = e0 + i;
    int d = (e < EE) ? ei[EE + e] : (int)(e - EE);
    atomicAdd(&cnt[d >> 9], 1);
  }
  __syncthreads();
  if (tid < 256) sc[tid] = (tid < NB) ? cnt[tid] : 0;
  __syncthreads();
  for (int o = 1; o < 256; o <<= 1) {
    int u = (tid < 256 && tid >= o) ? sc[tid - o] : 0;
    __syncthreads();
    if (tid < 256) sc[tid] += u;
    __syncthreads();
  }
  if (tid < NB) lbase[tid] = sc[tid] - cnt[tid];
  __syncthreads();
  if (tid < NB) {
    int c = cnt[tid];
    gbase[tid] = c ? atomicAdd(&gcur[tid], c) : 0;
    cnt[tid] = 0;
  }
  __syncthreads();
  for (int i = tid; i < nedge; i += 512) {
    long e = e0 + i;
    int s, d;
    if (e < EE) { s = ei[e]; d = ei[EE + e]; }
    else { s = (int)(e - EE); d = s; }
    int b = d >> 9;
    int r = atomicAdd(&cnt[b], 1);
    buf[lbase[b] + r] = make_int2(s, d);
  }
  __syncthreads();
  for (int i = tid; i < nedge; i += 512) {
    int2 ed = buf[i];
    int b = ed.y >> 9;
    bedge[gbase[b] + (i - lbase[b])] = ed;
  }
}

// per-bucket: LDS node-degree count + scan -> rp; LDS cursors -> esrc
__global__ __launch_bounds__(512) void k_csr(const int* __restrict__ boff,
                                             const int2* __restrict__ bedge,
                                             int* __restrict__ rp, int* __restrict__ esrc) {
  __shared__ int sdeg[BWID];
  __shared__ int sscan[BWID];
  int b = blockIdx.x, t = threadIdx.x;
  int n0 = b * BWID;
  int lo = boff[b], hi = boff[b + 1];
  sdeg[t] = 0;
  __syncthreads();
  for (int i = lo + t; i < hi; i += 512) {
    int2 ed = bedge[i];
    atomicAdd(&sdeg[ed.y - n0], 1);
  }
  __syncthreads();
  int v = sdeg[t];
  sscan[t] = v;
  __syncthreads();
  for (int o = 1; o < 512; o <<= 1) {
    int u = (t >= o) ? sscan[t - o] : 0;
    __syncthreads();
    sscan[t] += u;
    __syncthreads();
  }
  int excl = sscan[t] - v;
  int n = n0 + t;
  if (n < NN) rp[n] = lo + excl;
  if (b == NB - 1 && t == 0) rp[NN] = ET;
  __syncthreads();
  sdeg[t] = lo + excl;   // reuse as cursor
  __syncthreads();
  for (int i = lo + t; i < hi; i += 512) {
    int2 ed = bedge[i];
    int p = atomicAdd(&sdeg[ed.y - n0], 1);
    esrc[p] = ed.x;
  }
}

// ======================= layer-1 transform (8-node register blocking) =======================
// block 256 = 16 col-threads x 16 node-groups; thread computes 8 nodes x 4 cols.
// Same 4 W-float4 LDS reads per 4-k chunk now feed 128 FMAs -> VALU-bound, not LDS-bound.
#define FMA4A(a, xv) \
  a.x += xv.x*w0.x + xv.y*w1.x + xv.z*w2.x + xv.w*w3.x; \
  a.y += xv.x*w0.y + xv.y*w1.y + xv.z*w2.y + xv.w*w3.y; \
  a.z += xv.x*w0.z + xv.y*w1.z + xv.z*w2.z + xv.w*w3.z; \
  a.w += xv.x*w0.w + xv.y*w1.w + xv.z*w2.w + xv.w*w3.w;

__global__ __launch_bounds__(256) void k_xform1(
    const float* __restrict__ x,
    const float* __restrict__ Wl, const float* __restrict__ bl,
    const float* __restrict__ Wr, const float* __restrict__ br,
    unsigned short* __restrict__ xl1b, float* __restrict__ xr1) {
  __shared__ float Wlds[128 * 64];   // 32 KB: half of K at a time
  int tid = threadIdx.x;
  int ci = tid & 15, ni = tid >> 4;
  int cbase = ci * 4;
  int n0 = blockIdx.x * 128 + ni * 8;
  const float* xb[8];
#pragma unroll
  for (int j = 0; j < 8; ++j) {
    int r = n0 + j < NN ? n0 + j : NN - 1;
    xb[j] = x + (size_t)r * 256;
  }
  float4 acc[8];
#pragma unroll
  for (int j = 0; j < 8; ++j) acc[j] = make_float4(0.f, 0.f, 0.f, 0.f);

  for (int half = 0; half < 2; ++half) {
    int k0 = half * 128;
    __syncthreads();
    for (int i = tid; i < 128 * 64; i += 256) {
      int k = (i >> 6) + k0, c = i & 63;
      Wlds[i] = (c < 32) ? Wl[k * 32 + c] : Wr[k * 32 + (c - 32)];
    }
    __syncthreads();
    for (int kk = 0; kk < 128; kk += 4) {
      int k = k0 + kk;
      float4 xv[8];
#pragma unroll
      for (int j = 0; j < 8; ++j) xv[j] = *(const float4*)(xb[j] + k);
      const float* wr = &Wlds[kk * 64 + cbase];
      float4 w0 = *(const float4*)(wr);
      float4 w1 = *(const float4*)(wr + 64);
      float4 w2 = *(const float4*)(wr + 128);
      float4 w3 = *(const float4*)(wr + 192);
#pragma unroll
      for (int j = 0; j < 8; ++j) { FMA4A(acc[j], xv[j]) }
    }
  }
  if (cbase < 32) {
    float4 bv = { bl[cbase], bl[cbase+1], bl[cbase+2], bl[cbase+3] };
#pragma unroll
    for (int j = 0; j < 8; ++j) {
      int n = n0 + j;
      if (n < NN) {
        uint2 o = { pack_bf2(acc[j].x + bv.x, acc[j].y + bv.y),
                    pack_bf2(acc[j].z + bv.z, acc[j].w + bv.w) };
        *(uint2*)(xl1b + (size_t)n * 32 + cbase) = o;
      }
    }
  } else {
    int c2 = cbase - 32;
    float4 bv = { br[c2], br[c2+1], br[c2+2], br[c2+3] };
#pragma unroll
    for (int j = 0; j < 8; ++j) {
      int n = n0 + j;
      if (n < NN) {
        float4 o = { acc[j].x + bv.x, acc[j].y + bv.y, acc[j].z + bv.z, acc[j].w + bv.w };
        *(float4*)(xr1 + (size_t)n * 32 + c2) = o;
      }
    }
  }
}

// ======================= layer-1 gather (bf16 xl), unroll x4 =======================
__global__ __launch_bounds__(256) void k_gather1(
    const int* __restrict__ rp, const int* __restrict__ esrc,
    const unsigned short* __restrict__ xl1b, const float* __restrict__ xr1,
    const float* __restrict__ att1, const float* __restrict__ bias1,
    float* __restrict__ h) {
  int n = blockIdx.x * 8 + (threadIdx.x >> 5);
  if (n >= NN) return;
  int l = threadIdx.x & 31;
  float av = att1[l];
  float xr = xr1[(size_t)n * 32 + l];
  int rpn = rp[n], dg = rp[n + 1] - rpn;
  float acc = 0.0f, den = 0.0f;
  int j = 0;
  for (; j + 4 <= dg; j += 4) {
    int s0 = esrc[rpn + j + 0];
    int s1 = esrc[rpn + j + 1];
    int s2 = esrc[rpn + j + 2];
    int s3 = esrc[rpn + j + 3];
    float x0 = bf_lo(xl1b[(size_t)s0 * 32 + l]);
    float x1 = bf_lo(xl1b[(size_t)s1 * 32 + l]);
    float x2 = bf_lo(xl1b[(size_t)s2 * 32 + l]);
    float x3 = bf_lo(xl1b[(size_t)s3 * 32 + l]);
    float p0 = lrelu(x0 + xr) * av;
    float p1 = lrelu(x1 + xr) * av;
    float p2 = lrelu(x2 + xr) * av;
    float p3 = lrelu(x3 + xr) * av;
    p0 += __shfl_xor(p0, 1); p1 += __shfl_xor(p1, 1);
    p2 += __shfl_xor(p2, 1); p3 += __shfl_xor(p3, 1);
    p0 += __shfl_xor(p0, 2); p1 += __shfl_xor(p1, 2);
    p2 += __shfl_xor(p2, 2); p3 += __shfl_xor(p3, 2);
    float w0 = __expf(p0), w1 = __expf(p1), w2 = __expf(p2), w3 = __expf(p3);
    den += w0 + w1 + w2 + w3;
    acc += w0 * x0 + w1 * x1 + w2 * x2 + w3 * x3;
  }
  for (; j < dg; ++j) {
    int s = esrc[rpn + j];
    float xl = bf_lo(xl1b[(size_t)s * 32 + l]);
    float p = lrelu(xl + xr) * av;
    p += __shfl_xor(p, 1);
    p += __shfl_xor(p, 2);
    float w = __expf(p);
    den += w;
    acc += w * xl;
  }
  float v = acc / (den + 1e-16f) + bias1[l];
  h[(size_t)n * 32 + l] = v > 0.0f ? v : expm1f(v);
}

// ======================= layer-2 transform (4-node register blocking) =======================
__global__ __launch_bounds__(256) void k_xform2(
    const float* __restrict__ h,
    const float* __restrict__ Wl, const float* __restrict__ bl,
    const float* __restrict__ Wr, const float* __restrict__ br,
    unsigned short* __restrict__ hl2b, float* __restrict__ hr2) {
  __shared__ float Wlds[32 * 128];   // 16 KB
  int tid = threadIdx.x;
  for (int i = tid; i < 32 * 128; i += 256) {
    int k = i >> 7, c = i & 127;
    Wlds[i] = (c < 64) ? Wl[k * 64 + c] : Wr[k * 64 + (c - 64)];
  }
  __syncthreads();
  int ci = tid & 31, ni = tid >> 5;
  int cbase = ci * 4;
  int n0 = blockIdx.x * 32 + ni * 4;   // grid 3125 * 32 = 100000 exact
  const float* hb0 = h + (size_t)(n0 + 0) * 32;
  const float* hb1 = h + (size_t)(n0 + 1) * 32;
  const float* hb2 = h + (size_t)(n0 + 2) * 32;
  const float* hb3 = h + (size_t)(n0 + 3) * 32;
  float4 acc0 = {0,0,0,0}, acc1 = {0,0,0,0}, acc2 = {0,0,0,0}, acc3 = {0,0,0,0};
#pragma unroll
  for (int k = 0; k < 32; k += 4) {
    float4 xv0 = *(const float4*)(hb0 + k);
    float4 xv1 = *(const float4*)(hb1 + k);
    float4 xv2 = *(const float4*)(hb2 + k);
    float4 xv3 = *(const float4*)(hb3 + k);
    const float* wr = &Wlds[k * 128 + cbase];
    float4 w0 = *(const float4*)(wr);
    float4 w1 = *(const float4*)(wr + 128);
    float4 w2 = *(const float4*)(wr + 256);
    float4 w3 = *(const float4*)(wr + 384);
    FMA4A(acc0, xv0)
    FMA4A(acc1, xv1)
    FMA4A(acc2, xv2)
    FMA4A(acc3, xv3)
  }
  float4 acc[4] = {acc0, acc1, acc2, acc3};
  if (cbase < 64) {
    float4 bv = { bl[cbase], bl[cbase+1], bl[cbase+2], bl[cbase+3] };
#pragma unroll
    for (int j = 0; j < 4; ++j) {
      uint2 o = { pack_bf2(acc[j].x + bv.x, acc[j].y + bv.y),
                  pack_bf2(acc[j].z + bv.z, acc[j].w + bv.w) };
      *(uint2*)(hl2b + (size_t)(n0 + j) * 64 + cbase) = o;
    }
  } else {
    int c2 = cbase - 64;
    float4 bv = { br[c2], br[c2+1], br[c2+2], br[c2+3] };
#pragma unroll
    for (int j = 0; j < 4; ++j) {
      float4 o = { acc[j].x + bv.x, acc[j].y + bv.y, acc[j].z + bv.z, acc[j].w + bv.w };
      *(float4*)(hr2 + (size_t)(n0 + j) * 64 + c2) = o;
    }
  }
}

// ======================= layer-2 gather (bf16 hl) + fused pooling =======================
// 8 lanes/node, 32 contiguous nodes/block; block-local LDS pool (batch sorted ->
// <=4 graphs per block), flushed with ~130 global atomics/block. No out2 buffer.
__global__ __launch_bounds__(256) void k_gather2(
    const int* __restrict__ rp, const int* __restrict__ esrc,
    const unsigned short* __restrict__ hl2b, const float* __restrict__ hr2,
    const float* __restrict__ att2, const float* __restrict__ bias2,
    const int* __restrict__ batch,
    float* __restrict__ pool, float* __restrict__ cntg) {
  __shared__ float ssum[4][64];
  __shared__ float scnt[4];
  int tid = threadIdx.x;
  int n = (blockIdx.x * 256 + tid) >> 3;
  int l8 = tid & 7;
  int nblk0 = blockIdx.x * 32;
  int gmin = batch[nblk0];
  int gspan = batch[nblk0 + 31] - gmin + 1;   // <=4 (min graph size >> 32)
  ssum[tid >> 6][tid & 63] = 0.0f;
  if (tid < 4) scnt[tid] = 0.0f;
  __syncthreads();

  float4 ac0 = *(const float4*)(att2 + l8 * 8);
  float4 ac1 = *(const float4*)(att2 + l8 * 8 + 4);
  float4 bs0 = *(const float4*)(bias2 + l8 * 8);
  float4 bs1 = *(const float4*)(bias2 + l8 * 8 + 4);
  const float4* hrp = (const float4*)(hr2 + (size_t)n * 64 + l8 * 8);
  float4 hr0 = hrp[0], hr1 = hrp[1];
  int rpn = rp[n], dg = rp[n + 1] - rpn;
  float4 a0 = {0,0,0,0}, a1 = {0,0,0,0};
  float den = 0.0f;
  int j = 0;
  for (; j + 2 <= dg; j += 2) {
    int s0 = esrc[rpn + j];
    int s1 = esrc[rpn + j + 1];
    uint4 q0 = *(const uint4*)(hl2b + (size_t)s0 * 64 + l8 * 8);
    uint4 q1 = *(const uint4*)(hl2b + (size_t)s1 * 64 + l8 * 8);
    float4 u0 = { bf_lo(q0.x), bf_hi(q0.x), bf_lo(q0.y), bf_hi(q0.y) };
    float4 u1 = { bf_lo(q0.z), bf_hi(q0.z), bf_lo(q0.w), bf_hi(q0.w) };
    float4 v0 = { bf_lo(q1.x), bf_hi(q1.x), bf_lo(q1.y), bf_hi(q1.y) };
    float4 v1 = { bf_lo(q1.z), bf_hi(q1.z), bf_lo(q1.w), bf_hi(q1.w) };
    float p0 = lrelu(u0.x + hr0.x) * ac0.x + lrelu(u0.y + hr0.y) * ac0.y
             + lrelu(u0.z + hr0.z) * ac0.z + lrelu(u0.w + hr0.w) * ac0.w
             + lrelu(u1.x + hr1.x) * ac1.x + lrelu(u1.y + hr1.y) * ac1.y
             + lrelu(u1.z + hr1.z) * ac1.z + lrelu(u1.w + hr1.w) * ac1.w;
    float p1 = lrelu(v0.x + hr0.x) * ac0.x + lrelu(v0.y + hr0.y) * ac0.y
             + lrelu(v0.z + hr0.z) * ac0.z + lrelu(v0.w + hr0.w) * ac0.w
             + lrelu(v1.x + hr1.x) * ac1.x + lrelu(v1.y + hr1.y) * ac1.y
             + lrelu(v1.z + hr1.z) * ac1.z + lrelu(v1.w + hr1.w) * ac1.w;
    p0 += __shfl_xor(p0, 1); p1 += __shfl_xor(p1, 1);
    p0 += __shfl_xor(p0, 2); p1 += __shfl_xor(p1, 2);
    p0 += __shfl_xor(p0, 4); p1 += __shfl_xor(p1, 4);
    float w0 = __expf(p0), w1 = __expf(p1);
    den += w0 + w1;
    a0.x += w0 * u0.x + w1 * v0.x; a0.y += w0 * u0.y + w1 * v0.y;
    a0.z += w0 * u0.z + w1 * v0.z; a0.w += w0 * u0.w + w1 * v0.w;
    a1.x += w0 * u1.x + w1 * v1.x; a1.y += w0 * u1.y + w1 * v1.y;
    a1.z += w0 * u1.z + w1 * v1.z; a1.w += w0 * u1.w + w1 * v1.w;
  }
  for (; j < dg; ++j) {
    int s = esrc[rpn + j];
    uint4 q0 = *(const uint4*)(hl2b + (size_t)s * 64 + l8 * 8);
    float4 u0 = { bf_lo(q0.x), bf_hi(q0.x), bf_lo(q0.y), bf_hi(q0.y) };
    float4 u1 = { bf_lo(q0.z), bf_hi(q0.z), bf_lo(q0.w), bf_hi(q0.w) };
    float p = lrelu(u0.x + hr0.x) * ac0.x + lrelu(u0.y + hr0.y) * ac0.y
            + lrelu(u0.z + hr0.z) * ac0.z + lrelu(u0.w + hr0.w) * ac0.w
            + lrelu(u1.x + hr1.x) * ac1.x + lrelu(u1.y + hr1.y) * ac1.y
            + lrelu(u1.z + hr1.z) * ac1.z + lrelu(u1.w + hr1.w) * ac1.w;
    p += __shfl_xor(p, 1);
    p += __shfl_xor(p, 2);
    p += __shfl_xor(p, 4);
    float w = __expf(p);
    den += w;
    a0.x += w * u0.x; a0.y += w * u0.y; a0.z += w * u0.z; a0.w += w * u0.w;
    a1.x += w * u1.x; a1.y += w * u1.y; a1.z += w * u1.z; a1.w += w * u1.w;
  }
  float inv = 1.0f / (den + 1e-16f);
  int gi = batch[n] - gmin;
  float* sp = &ssum[gi][l8 * 8];
  atomicAdd(sp + 0, a0.x * inv + bs0.x);
  atomicAdd(sp + 1, a0.y * inv + bs0.y);
  atomicAdd(sp + 2, a0.z * inv + bs0.z);
  atomicAdd(sp + 3, a0.w * inv + bs0.w);
  atomicAdd(sp + 4, a1.x * inv + bs1.x);
  atomicAdd(sp + 5, a1.y * inv + bs1.y);
  atomicAdd(sp + 6, a1.z * inv + bs1.z);
  atomicAdd(sp + 7, a1.w * inv + bs1.w);
  if (l8 == 0) atomicAdd(&scnt[gi], 1.0f);
  __syncthreads();
  for (int i = tid; i < gspan * 64; i += 256)
    atomicAdd(pool + (size_t)(gmin + (i >> 6)) * 64 + (i & 63), ssum[i >> 6][i & 63]);
  if (tid < gspan) atomicAdd(cntg + gmin + tid, scnt[tid]);
}

__global__ __launch_bounds__(256) void k_final(
    const float* __restrict__ pool, const float* __restrict__ cntg,
    float* __restrict__ out) {
  int i = blockIdx.x * 256 + threadIdx.x;
  if (i < NG * 64) out[i] = pool[i] / fmaxf(cntg[i >> 6], 1.0f);
}

extern "C" void kernel_launch(void* const* d_in, const int* in_sizes, int n_in,
                              void* d_out, int out_size, void* d_ws, size_t ws_size,
                              hipStream_t stream) {
  const float* x     = (const float*)d_in[0];
  const int*   ei    = (const int*)d_in[1];
  const int*   batch = (const int*)d_in[2];
  const float* W1l   = (const float*)d_in[3];
  const float* b1l   = (const float*)d_in[4];
  const float* W1r   = (const float*)d_in[5];
  const float* b1r   = (const float*)d_in[6];
  const float* att1  = (const float*)d_in[7];
  const float* bias1 = (const float*)d_in[8];
  const float* W2l   = (const float*)d_in[9];
  const float* b2l   = (const float*)d_in[10];
  const float* W2r   = (const float*)d_in[11];
  const float* b2r   = (const float*)d_in[12];
  const float* att2  = (const float*)d_in[13];
  const float* bias2 = (const float*)d_in[14];
  float* ws = (float*)d_ws;
  int*   wi = (int*)d_ws;
  float* out = (float*)d_out;

  // zero pool + cntg + bcnt (contiguous region)
  hipMemsetAsync(ws + OFF_POOL, 0, (size_t)(WS_UNITS - OFF_POOL) * 4, stream);

  // CSR build via bucket counting sort (LDS-reorder partition)
  k_bcount<<<512, 256, 0, stream>>>(ei, wi + OFF_BCNT);
  k_bscan<<<1, 256, 0, stream>>>(wi + OFF_BCNT, wi + OFF_BOFF, wi + OFF_GCUR);
  k_part<<<PBLOCKS, 512, 0, stream>>>(ei, wi + OFF_GCUR, (int2*)(wi + OFF_BEDGE));
  k_csr<<<NB, 512, 0, stream>>>(wi + OFF_BOFF, (const int2*)(wi + OFF_BEDGE),
                                wi + OFF_RP, wi + OFF_ESRC);

  // layer 1
  k_xform1<<<(NN + 127) / 128, 256, 0, stream>>>(x, W1l, b1l, W1r, b1r,
                                                 (unsigned short*)(ws + OFF_XL1B), ws + OFF_XR1);
  k_gather1<<<NN / 8, 256, 0, stream>>>(wi + OFF_RP, wi + OFF_ESRC,
                                        (const unsigned short*)(ws + OFF_XL1B), ws + OFF_XR1,
                                        att1, bias1, ws + OFF_H);
  // layer 2 (xform2 overwrites bedge region — bedge is dead by then)
  k_xform2<<<NN / 32, 256, 0, stream>>>(ws + OFF_H, W2l, b2l, W2r, b2r,
                                        (unsigned short*)(ws + OFF_HL2B), ws + OFF_HR2);
  k_gather2<<<(NN * 8 + 255) / 256, 256, 0, stream>>>(wi + OFF_RP, wi + OFF_ESRC,
                                                      (const unsigned short*)(ws + OFF_HL2B),
                                                      ws + OFF_HR2, att2, bias2, batch,
                                                      ws + OFF_POOL, ws + OFF_CNTG);
  k_final<<<16, 256, 0, stream>>>(ws + OFF_POOL, ws + OFF_CNTG, out);
}